// Round 1
// baseline (853.279 us; speedup 1.0000x reference)
//
#include <hip/hip_runtime.h>

#define TTOK 2048
#define HIDN 4096
#define OPD  6144
#define DH   128
#define VD   256
#define KOFF 4096
#define VOFF 5120

typedef short  s16x8 __attribute__((ext_vector_type(8)));
typedef unsigned short u16x8 __attribute__((ext_vector_type(8)));
typedef float  fx4   __attribute__((ext_vector_type(4)));

constexpr float LAM_INIT = 0.7455692280263534f;
constexpr float OML      = 1.0f - LAM_INIT;          // (1 - lambda_init)
constexpr float QKSCALE  = 0.08838834764831845f;     // 128^-0.5

__device__ __forceinline__ unsigned short f2bf(float f) {
  unsigned int u = __builtin_bit_cast(unsigned int, f);
  u += 0x7fffu + ((u >> 16) & 1u);   // RNE
  return (unsigned short)(u >> 16);
}

// C[M,N] = A[M,K] * B[N,K]^T + bias.  A: fp32 or bf16 row-major, B: fp32 row-major.
// OUTBF16: C written as bf16, else fp32.  WVT: blocks with n0>=VOFF write V^T
// (vt[(col-VOFF)*TTOK + row]) instead of C.
template<bool ABF16, bool OUTBF16, bool WVT>
__global__ __launch_bounds__(256)
void gemm_bt(const void* __restrict__ Ap, const void* __restrict__ Bp,
             const float* __restrict__ bias, void* __restrict__ Cp,
             unsigned short* __restrict__ vt,
             int K, int lda, int ldb, int ldc)
{
  __shared__ unsigned short As[128 * 40];
  __shared__ unsigned short Bs[128 * 40];
  const int tid  = threadIdx.x;
  const int lane = tid & 63, wid = tid >> 6;
  const int wr = wid >> 1, wc = wid & 1;       // 2x2 wave grid, 64x64 out each
  const int m0 = blockIdx.y * 128, n0 = blockIdx.x * 128;
  const int l15 = lane & 15, lg = lane >> 4;

  fx4 acc[4][4] = {};

  for (int kt = 0; kt < K; kt += 32) {
    #pragma unroll
    for (int it = 0; it < 2; ++it) {
      const int slot = it * 256 + tid;
      const int row  = slot >> 2;
      const int c8   = (slot & 3) << 3;
      u16x8 va, vb;
      if (ABF16) {
        va = *(const u16x8*)((const unsigned short*)Ap + (size_t)(m0 + row) * lda + kt + c8);
      } else {
        const float* ap = (const float*)Ap + (size_t)(m0 + row) * lda + kt + c8;
        const float4 a0 = *(const float4*)ap;
        const float4 a1 = *(const float4*)(ap + 4);
        va[0]=f2bf(a0.x); va[1]=f2bf(a0.y); va[2]=f2bf(a0.z); va[3]=f2bf(a0.w);
        va[4]=f2bf(a1.x); va[5]=f2bf(a1.y); va[6]=f2bf(a1.z); va[7]=f2bf(a1.w);
      }
      {
        const float* bp = (const float*)Bp + (size_t)(n0 + row) * ldb + kt + c8;
        const float4 b0 = *(const float4*)bp;
        const float4 b1 = *(const float4*)(bp + 4);
        vb[0]=f2bf(b0.x); vb[1]=f2bf(b0.y); vb[2]=f2bf(b0.z); vb[3]=f2bf(b0.w);
        vb[4]=f2bf(b1.x); vb[5]=f2bf(b1.y); vb[6]=f2bf(b1.z); vb[7]=f2bf(b1.w);
      }
      *(u16x8*)&As[row * 40 + c8] = va;
      *(u16x8*)&Bs[row * 40 + c8] = vb;
    }
    __syncthreads();
    s16x8 af[4], bf[4];
    #pragma unroll
    for (int i = 0; i < 4; ++i) {
      af[i] = *(const s16x8*)&As[(wr * 64 + i * 16 + l15) * 40 + lg * 8];
      bf[i] = *(const s16x8*)&Bs[(wc * 64 + i * 16 + l15) * 40 + lg * 8];
    }
    #pragma unroll
    for (int mi = 0; mi < 4; ++mi)
      #pragma unroll
      for (int ni = 0; ni < 4; ++ni)
        acc[mi][ni] = __builtin_amdgcn_mfma_f32_16x16x32_bf16(af[mi], bf[ni], acc[mi][ni], 0, 0, 0);
    __syncthreads();
  }

  const int r0 = m0 + wr * 64;
  const int c0 = n0 + wc * 64;
  if (WVT && n0 >= VOFF) {
    #pragma unroll
    for (int mi = 0; mi < 4; ++mi)
      #pragma unroll
      for (int ni = 0; ni < 4; ++ni) {
        const int col = c0 + ni * 16 + l15;
        const float bv = bias[col];
        const fx4 a = acc[mi][ni];
        ushort4 pk;
        pk.x = f2bf(a[0] + bv); pk.y = f2bf(a[1] + bv);
        pk.z = f2bf(a[2] + bv); pk.w = f2bf(a[3] + bv);
        const int row0 = r0 + mi * 16 + lg * 4;   // 4 consecutive t
        *(ushort4*)&vt[(size_t)(col - VOFF) * TTOK + row0] = pk;
      }
  } else {
    #pragma unroll
    for (int mi = 0; mi < 4; ++mi)
      #pragma unroll
      for (int ni = 0; ni < 4; ++ni) {
        const int col = c0 + ni * 16 + l15;
        const float bv = bias[col];
        const fx4 a = acc[mi][ni];
        #pragma unroll
        for (int jj = 0; jj < 4; ++jj) {
          const int row = r0 + mi * 16 + lg * 4 + jj;
          const float v = a[jj] + bv;
          if (OUTBF16) ((unsigned short*)Cp)[(size_t)row * ldc + col] = f2bf(v);
          else         ((float*)Cp)[(size_t)row * ldc + col] = v;
        }
      }
  }
}

// One block = one (pair, 16-row q tile).  Wave 0 = component 0, wave 1 = component 1.
// Flash attention with per-component online softmax; final combine + RMSNorm.
__global__ __launch_bounds__(128)
void attn_kernel(const unsigned short* __restrict__ qkv,   // [TTOK][OPD] bf16 (Q,K regions)
                 const unsigned short* __restrict__ vt,    // [1024][TTOK] bf16 = V^T
                 const float* __restrict__ lq1, const float* __restrict__ lk1,
                 const float* __restrict__ lq2, const float* __restrict__ lk2,
                 const float* __restrict__ subln,
                 unsigned short* __restrict__ attn_out)    // [TTOK][HIDN] bf16
{
  __shared__ unsigned short Plds[2 * 16 * 40];
  __shared__ float Ocomb[16 * 256];
  const int pair = blockIdx.x;
  const int q0   = blockIdx.y * 16;
  const int tid  = threadIdx.x;
  const int lane = tid & 63;
  const int comp = tid >> 6;
  const int l15 = lane & 15, lg = lane >> 4;
  const int kvp = pair >> 2;   // GQA: query pair -> kv pair

  float dd1 = 0.f, dd2 = 0.f;
  for (int i = 0; i < DH; ++i) { dd1 += lq1[i] * lk1[i]; dd2 += lq2[i] * lk2[i]; }
  const float lam = __expf(dd1) - __expf(dd2) + LAM_INIT;

  const int qcol = pair * VD + comp * DH;
  const int kcol = KOFF + kvp * VD + comp * DH;

  s16x8 qf[4];
  {
    const unsigned short* qb = qkv + (size_t)(q0 + l15) * OPD + qcol + lg * 8;
    #pragma unroll
    for (int kf = 0; kf < 4; ++kf) qf[kf] = *(const s16x8*)(qb + kf * 32);
  }

  float mrun[4], lrun[4];
  #pragma unroll
  for (int j = 0; j < 4; ++j) { mrun[j] = -1e30f; lrun[j] = 0.f; }
  fx4 oacc[16] = {};

  const unsigned short* vbase = vt + (size_t)(kvp * VD) * TTOK;
  unsigned short* pl = Plds + comp * 640;

  const int nkt = (q0 + 15) / 32 + 1;
  for (int kt = 0; kt < nkt; ++kt) {
    const int kb = kt * 32;
    fx4 s0 = {0.f, 0.f, 0.f, 0.f}, s1 = {0.f, 0.f, 0.f, 0.f};
    const unsigned short* kp = qkv + (size_t)(kb + l15) * OPD + kcol + lg * 8;
    #pragma unroll
    for (int kf = 0; kf < 4; ++kf) {
      const s16x8 k0 = *(const s16x8*)(kp + kf * 32);
      const s16x8 k1 = *(const s16x8*)(kp + (size_t)16 * OPD + kf * 32);
      s0 = __builtin_amdgcn_mfma_f32_16x16x32_bf16(qf[kf], k0, s0, 0, 0, 0);
      s1 = __builtin_amdgcn_mfma_f32_16x16x32_bf16(qf[kf], k1, s1, 0, 0, 0);
    }
    float fac[4];
    #pragma unroll
    for (int jj = 0; jj < 4; ++jj) {
      const int q = q0 + lg * 4 + jj;
      float v0 = (kb + l15      <= q) ? s0[jj] * QKSCALE : -1e30f;
      float v1 = (kb + 16 + l15 <= q) ? s1[jj] * QKSCALE : -1e30f;
      float mx = fmaxf(v0, v1);
      mx = fmaxf(mx, __shfl_xor(mx, 1));
      mx = fmaxf(mx, __shfl_xor(mx, 2));
      mx = fmaxf(mx, __shfl_xor(mx, 4));
      mx = fmaxf(mx, __shfl_xor(mx, 8));
      const float mnew = fmaxf(mrun[jj], mx);
      const float p0 = __expf(v0 - mnew);
      const float p1 = __expf(v1 - mnew);
      float rs = p0 + p1;
      rs += __shfl_xor(rs, 1);
      rs += __shfl_xor(rs, 2);
      rs += __shfl_xor(rs, 4);
      rs += __shfl_xor(rs, 8);
      fac[jj]  = __expf(mrun[jj] - mnew);
      lrun[jj] = lrun[jj] * fac[jj] + rs;
      mrun[jj] = mnew;
      const int qrow = lg * 4 + jj;
      pl[qrow * 40 + l15]      = f2bf(p0);
      pl[qrow * 40 + 16 + l15] = f2bf(p1);
    }
    #pragma unroll
    for (int nf = 0; nf < 16; ++nf)
      #pragma unroll
      for (int jj = 0; jj < 4; ++jj)
        oacc[nf][jj] *= fac[jj];
    __syncthreads();
    const s16x8 pa = *(const s16x8*)&pl[l15 * 40 + lg * 8];
    #pragma unroll
    for (int nf = 0; nf < 16; ++nf) {
      const s16x8 vf = *(const s16x8*)(vbase + (size_t)(nf * 16 + l15) * TTOK + kb + lg * 8);
      oacc[nf] = __builtin_amdgcn_mfma_f32_16x16x32_bf16(pa, vf, oacc[nf], 0, 0, 0);
    }
    __syncthreads();
  }

  float linv[4];
  #pragma unroll
  for (int jj = 0; jj < 4; ++jj) linv[jj] = 1.0f / lrun[jj];

  if (comp == 1) {
    #pragma unroll
    for (int nf = 0; nf < 16; ++nf)
      #pragma unroll
      for (int jj = 0; jj < 4; ++jj)
        Ocomb[(lg * 4 + jj) * 256 + nf * 16 + l15] = oacc[nf][jj] * linv[jj];
  }
  __syncthreads();
  if (comp == 0) {
    float ss[4] = {0.f, 0.f, 0.f, 0.f};
    #pragma unroll
    for (int nf = 0; nf < 16; ++nf)
      #pragma unroll
      for (int jj = 0; jj < 4; ++jj) {
        const float v = oacc[nf][jj] * linv[jj] - lam * Ocomb[(lg * 4 + jj) * 256 + nf * 16 + l15];
        oacc[nf][jj] = v;
        ss[jj] += v * v;
      }
    #pragma unroll
    for (int jj = 0; jj < 4; ++jj) {
      ss[jj] += __shfl_xor(ss[jj], 1);
      ss[jj] += __shfl_xor(ss[jj], 2);
      ss[jj] += __shfl_xor(ss[jj], 4);
      ss[jj] += __shfl_xor(ss[jj], 8);
      ss[jj] = rsqrtf(ss[jj] * (1.0f / 256.0f) + 1e-5f) * OML;
    }
    #pragma unroll
    for (int nf = 0; nf < 16; ++nf) {
      const int dcol = nf * 16 + l15;
      const float sw = subln[dcol];
      #pragma unroll
      for (int jj = 0; jj < 4; ++jj) {
        const int t = q0 + lg * 4 + jj;
        attn_out[(size_t)t * HIDN + pair * VD + dcol] = f2bf(oacc[nf][jj] * ss[jj] * sw);
      }
    }
  }
}

extern "C" void kernel_launch(void* const* d_in, const int* in_sizes, int n_in,
                              void* d_out, int out_size, void* d_ws, size_t ws_size,
                              hipStream_t stream) {
  (void)in_sizes; (void)n_in; (void)out_size; (void)ws_size;
  const float* hs     = (const float*)d_in[0];
  const float* wqkv_w = (const float*)d_in[1];
  const float* wqkv_b = (const float*)d_in[2];
  const float* lq1    = (const float*)d_in[3];
  const float* lk1    = (const float*)d_in[4];
  const float* lq2    = (const float*)d_in[5];
  const float* lk2    = (const float*)d_in[6];
  const float* subln  = (const float*)d_in[7];
  const float* out_w  = (const float*)d_in[8];
  const float* out_b  = (const float*)d_in[9];

  // ws layout (bf16): qkv [TTOK][OPD] | V^T [1024][TTOK] | attn_out [TTOK][HIDN]  (~46 MB)
  unsigned short* qkv      = (unsigned short*)d_ws;
  unsigned short* vt       = qkv + (size_t)TTOK * OPD;
  unsigned short* attn_out = vt + (size_t)1024 * TTOK;

  // GEMM1: qkv = hs @ wqkv_w^T + b   (V region diverted to V^T buffer)
  gemm_bt<false, true, true><<<dim3(OPD / 128, TTOK / 128), 256, 0, stream>>>(
      hs, wqkv_w, wqkv_b, qkv, vt, HIDN, HIDN, HIDN, OPD);

  // Attention + combine + RMSNorm -> attn_out (bf16)
  attn_kernel<<<dim3(16, TTOK / 16), 128, 0, stream>>>(
      qkv, vt, lq1, lk1, lq2, lk2, subln, attn_out);

  // GEMM2: out = attn_out @ out_w^T + out_b  (fp32 out)
  gemm_bt<true, false, false><<<dim3(HIDN / 128, TTOK / 128), 256, 0, stream>>>(
      attn_out, out_w, out_b, d_out, nullptr, HIDN, HIDN, HIDN, HIDN);
}

// Round 2
// 804.846 us; speedup vs baseline: 1.0602x; 1.0602x over previous
//
#include <hip/hip_runtime.h>

#define TTOK 2048
#define HIDN 4096
#define OPD  6144
#define DH   128
#define VD   256
#define KOFF 4096
#define VOFF 5120

typedef short  s16x8 __attribute__((ext_vector_type(8)));
typedef unsigned short u16x8 __attribute__((ext_vector_type(8)));
typedef float  fx4   __attribute__((ext_vector_type(4)));

constexpr float LAM_INIT = 0.7455692280263534f;
constexpr float OML      = 1.0f - LAM_INIT;          // (1 - lambda_init)
constexpr float QKSCALE  = 0.08838834764831845f;     // 128^-0.5
constexpr float RESCALE_THR = 8.0f;

__device__ __forceinline__ unsigned short f2bf(float f) {
  unsigned int u = __builtin_bit_cast(unsigned int, f);
  u += 0x7fffu + ((u >> 16) & 1u);   // RNE
  return (unsigned short)(u >> 16);
}

// C[M,N] = A[M,K] * B[N,K]^T + bias.  A: fp32 or bf16 row-major, B: fp32 row-major.
// OUTBF16: C written as bf16, else fp32.  WVT: blocks with n0>=VOFF write V^T
// (vt[(col-VOFF)*TTOK + row]) instead of C.
template<bool ABF16, bool OUTBF16, bool WVT>
__global__ __launch_bounds__(256)
void gemm_bt(const void* __restrict__ Ap, const void* __restrict__ Bp,
             const float* __restrict__ bias, void* __restrict__ Cp,
             unsigned short* __restrict__ vt,
             int K, int lda, int ldb, int ldc)
{
  __shared__ unsigned short As[128 * 40];
  __shared__ unsigned short Bs[128 * 40];
  const int tid  = threadIdx.x;
  const int lane = tid & 63, wid = tid >> 6;
  const int wr = wid >> 1, wc = wid & 1;       // 2x2 wave grid, 64x64 out each
  const int m0 = blockIdx.y * 128, n0 = blockIdx.x * 128;
  const int l15 = lane & 15, lg = lane >> 4;

  fx4 acc[4][4] = {};

  for (int kt = 0; kt < K; kt += 32) {
    #pragma unroll
    for (int it = 0; it < 2; ++it) {
      const int slot = it * 256 + tid;
      const int row  = slot >> 2;
      const int c8   = (slot & 3) << 3;
      u16x8 va, vb;
      if (ABF16) {
        va = *(const u16x8*)((const unsigned short*)Ap + (size_t)(m0 + row) * lda + kt + c8);
      } else {
        const float* ap = (const float*)Ap + (size_t)(m0 + row) * lda + kt + c8;
        const float4 a0 = *(const float4*)ap;
        const float4 a1 = *(const float4*)(ap + 4);
        va[0]=f2bf(a0.x); va[1]=f2bf(a0.y); va[2]=f2bf(a0.z); va[3]=f2bf(a0.w);
        va[4]=f2bf(a1.x); va[5]=f2bf(a1.y); va[6]=f2bf(a1.z); va[7]=f2bf(a1.w);
      }
      {
        const float* bp = (const float*)Bp + (size_t)(n0 + row) * ldb + kt + c8;
        const float4 b0 = *(const float4*)bp;
        const float4 b1 = *(const float4*)(bp + 4);
        vb[0]=f2bf(b0.x); vb[1]=f2bf(b0.y); vb[2]=f2bf(b0.z); vb[3]=f2bf(b0.w);
        vb[4]=f2bf(b1.x); vb[5]=f2bf(b1.y); vb[6]=f2bf(b1.z); vb[7]=f2bf(b1.w);
      }
      *(u16x8*)&As[row * 40 + c8] = va;
      *(u16x8*)&Bs[row * 40 + c8] = vb;
    }
    __syncthreads();
    s16x8 af[4], bf[4];
    #pragma unroll
    for (int i = 0; i < 4; ++i) {
      af[i] = *(const s16x8*)&As[(wr * 64 + i * 16 + l15) * 40 + lg * 8];
      bf[i] = *(const s16x8*)&Bs[(wc * 64 + i * 16 + l15) * 40 + lg * 8];
    }
    #pragma unroll
    for (int mi = 0; mi < 4; ++mi)
      #pragma unroll
      for (int ni = 0; ni < 4; ++ni)
        acc[mi][ni] = __builtin_amdgcn_mfma_f32_16x16x32_bf16(af[mi], bf[ni], acc[mi][ni], 0, 0, 0);
    __syncthreads();
  }

  const int r0 = m0 + wr * 64;
  const int c0 = n0 + wc * 64;
  if (WVT && n0 >= VOFF) {
    #pragma unroll
    for (int mi = 0; mi < 4; ++mi)
      #pragma unroll
      for (int ni = 0; ni < 4; ++ni) {
        const int col = c0 + ni * 16 + l15;
        const float bv = bias[col];
        const fx4 a = acc[mi][ni];
        ushort4 pk;
        pk.x = f2bf(a[0] + bv); pk.y = f2bf(a[1] + bv);
        pk.z = f2bf(a[2] + bv); pk.w = f2bf(a[3] + bv);
        const int row0 = r0 + mi * 16 + lg * 4;   // 4 consecutive t
        *(ushort4*)&vt[(size_t)(col - VOFF) * TTOK + row0] = pk;
      }
  } else {
    #pragma unroll
    for (int mi = 0; mi < 4; ++mi)
      #pragma unroll
      for (int ni = 0; ni < 4; ++ni) {
        const int col = c0 + ni * 16 + l15;
        const float bv = bias[col];
        const fx4 a = acc[mi][ni];
        #pragma unroll
        for (int jj = 0; jj < 4; ++jj) {
          const int row = r0 + mi * 16 + lg * 4 + jj;
          const float v = a[jj] + bv;
          if (OUTBF16) ((unsigned short*)Cp)[(size_t)row * ldc + col] = f2bf(v);
          else         ((float*)Cp)[(size_t)row * ldc + col] = v;
        }
      }
  }
}

// One block = ONE WAVE = one (pair, 16-row q tile), BOTH differential components.
// Swapped QK^T (mfma(K,Q) -> S^T, lane owns one q-row), defer-max online softmax,
// per-lane partial row-sums (reduced once at the end), shared V fragments for
// both components' PV. No barriers; wave-local LDS for the P transpose only.
__global__ __launch_bounds__(64, 2)
void attn_kernel(const unsigned short* __restrict__ qkv,   // [TTOK][OPD] bf16 (Q,K regions)
                 const unsigned short* __restrict__ vt,    // [1024][TTOK] bf16 = V^T
                 const float* __restrict__ lq1, const float* __restrict__ lk1,
                 const float* __restrict__ lq2, const float* __restrict__ lk2,
                 const float* __restrict__ subln,
                 unsigned short* __restrict__ attn_out)    // [TTOK][HIDN] bf16
{
  __shared__ unsigned short Pl[2][16 * 40];
  const int lane = threadIdx.x;
  const int l15 = lane & 15, lg = lane >> 4;
  const int pair = blockIdx.x;
  const int yy   = blockIdx.y;
  const int qt   = (yy & 1) ? (127 - (yy >> 1)) : (yy >> 1);  // light/heavy interleave
  const int q0   = qt * 16;
  const int kvp  = pair >> 2;

  // lambda via wave-parallel dot (128 elems over 64 lanes)
  float a1 = lq1[lane] * lk1[lane] + lq1[lane + 64] * lk1[lane + 64];
  float a2 = lq2[lane] * lk2[lane] + lq2[lane + 64] * lk2[lane + 64];
  #pragma unroll
  for (int s = 1; s < 64; s <<= 1) { a1 += __shfl_xor(a1, s); a2 += __shfl_xor(a2, s); }
  const float lam = __expf(a1) - __expf(a2) + LAM_INIT;

  const int qcol = pair * VD;          // comp0 at +0, comp1 at +DH
  const int kcol = KOFF + kvp * VD;

  // Q fragments (B-operand): lane holds q-row = q0+l15, d-chunk lg*8 within kf*32
  s16x8 qf0[4], qf1[4];
  {
    const unsigned short* qb = qkv + (size_t)(q0 + l15) * OPD + qcol + lg * 8;
    #pragma unroll
    for (int kf = 0; kf < 4; ++kf) {
      qf0[kf] = *(const s16x8*)(qb + kf * 32);
      qf1[kf] = *(const s16x8*)(qb + DH + kf * 32);
    }
  }

  float mrun0 = -1e30f, mrun1 = -1e30f;
  float lrun0 = 0.f, lrun1 = 0.f;      // per-lane partial sums
  fx4 oacc0[16] = {}, oacc1[16] = {};

  const unsigned short* vbase = vt + (size_t)(kvp * VD) * TTOK;
  const int q = q0 + l15;              // this lane's q-row (swapped layout)
  const int nkt = q0 / 32 + 1;

  for (int kt = 0; kt < nkt; ++kt) {
    const int kb = kt * 32;
    // ---- QK^T swapped: S^T[key][q], frag rows = keys ----
    fx4 s00 = {0,0,0,0}, s01 = {0,0,0,0}, s10 = {0,0,0,0}, s11 = {0,0,0,0};
    {
      const unsigned short* kp = qkv + (size_t)(kb + l15) * OPD + kcol + lg * 8;
      #pragma unroll
      for (int kf = 0; kf < 4; ++kf) {
        const s16x8 k00 = *(const s16x8*)(kp + kf * 32);
        const s16x8 k01 = *(const s16x8*)(kp + (size_t)16 * OPD + kf * 32);
        s00 = __builtin_amdgcn_mfma_f32_16x16x32_bf16(k00, qf0[kf], s00, 0, 0, 0);
        s01 = __builtin_amdgcn_mfma_f32_16x16x32_bf16(k01, qf0[kf], s01, 0, 0, 0);
        const s16x8 k10 = *(const s16x8*)(kp + DH + kf * 32);
        const s16x8 k11 = *(const s16x8*)(kp + (size_t)16 * OPD + DH + kf * 32);
        s10 = __builtin_amdgcn_mfma_f32_16x16x32_bf16(k10, qf1[kf], s10, 0, 0, 0);
        s11 = __builtin_amdgcn_mfma_f32_16x16x32_bf16(k11, qf1[kf], s11, 0, 0, 0);
      }
    }
    // ---- mask + scale; lane holds keys kb+lg*4+j (lo) and kb+16+lg*4+j (hi) for q-row l15
    float v0[8], v1[8];
    #pragma unroll
    for (int j = 0; j < 4; ++j) {
      const int klo = kb + lg * 4 + j, khi = klo + 16;
      v0[j]     = (klo <= q) ? s00[j] * QKSCALE : -1e30f;
      v0[4 + j] = (khi <= q) ? s01[j] * QKSCALE : -1e30f;
      v1[j]     = (klo <= q) ? s10[j] * QKSCALE : -1e30f;
      v1[4 + j] = (khi <= q) ? s11[j] * QKSCALE : -1e30f;
    }
    // ---- tile max per comp: in-lane tree + 2 shfls (q-row parallel across l15)
    float tm0 = fmaxf(fmaxf(fmaxf(v0[0],v0[1]),fmaxf(v0[2],v0[3])),
                      fmaxf(fmaxf(v0[4],v0[5]),fmaxf(v0[6],v0[7])));
    float tm1 = fmaxf(fmaxf(fmaxf(v1[0],v1[1]),fmaxf(v1[2],v1[3])),
                      fmaxf(fmaxf(v1[4],v1[5]),fmaxf(v1[6],v1[7])));
    tm0 = fmaxf(tm0, __shfl_xor(tm0, 16)); tm0 = fmaxf(tm0, __shfl_xor(tm0, 32));
    tm1 = fmaxf(tm1, __shfl_xor(tm1, 16)); tm1 = fmaxf(tm1, __shfl_xor(tm1, 32));

    // ---- defer-max: rescale only when max grows past threshold (rare)
    const bool need = (tm0 > mrun0 + RESCALE_THR) || (tm1 > mrun1 + RESCALE_THR);
    if (__any(need)) {
      const float mn0 = fmaxf(mrun0, tm0), mn1 = fmaxf(mrun1, tm1);
      const float fac0 = __expf(mrun0 - mn0), fac1 = __expf(mrun1 - mn1);
      mrun0 = mn0; mrun1 = mn1;
      lrun0 *= fac0; lrun1 *= fac1;
      #pragma unroll
      for (int jj = 0; jj < 4; ++jj) {
        const float fr0 = __shfl(fac0, lg * 4 + jj);
        const float fr1 = __shfl(fac1, lg * 4 + jj);
        #pragma unroll
        for (int nf = 0; nf < 16; ++nf) { oacc0[nf][jj] *= fr0; oacc1[nf][jj] *= fr1; }
      }
    }

    // ---- P = exp(v - mrun); per-lane partial sum; pack bf16 into LDS (transpose)
    {
      float ps0 = 0.f, ps1 = 0.f;
      ushort4 lo0, hi0, lo1, hi1;
      float p;
      p = __expf(v0[0]-mrun0); ps0 += p; lo0.x = f2bf(p);
      p = __expf(v0[1]-mrun0); ps0 += p; lo0.y = f2bf(p);
      p = __expf(v0[2]-mrun0); ps0 += p; lo0.z = f2bf(p);
      p = __expf(v0[3]-mrun0); ps0 += p; lo0.w = f2bf(p);
      p = __expf(v0[4]-mrun0); ps0 += p; hi0.x = f2bf(p);
      p = __expf(v0[5]-mrun0); ps0 += p; hi0.y = f2bf(p);
      p = __expf(v0[6]-mrun0); ps0 += p; hi0.z = f2bf(p);
      p = __expf(v0[7]-mrun0); ps0 += p; hi0.w = f2bf(p);
      p = __expf(v1[0]-mrun1); ps1 += p; lo1.x = f2bf(p);
      p = __expf(v1[1]-mrun1); ps1 += p; lo1.y = f2bf(p);
      p = __expf(v1[2]-mrun1); ps1 += p; lo1.z = f2bf(p);
      p = __expf(v1[3]-mrun1); ps1 += p; lo1.w = f2bf(p);
      p = __expf(v1[4]-mrun1); ps1 += p; hi1.x = f2bf(p);
      p = __expf(v1[5]-mrun1); ps1 += p; hi1.y = f2bf(p);
      p = __expf(v1[6]-mrun1); ps1 += p; hi1.z = f2bf(p);
      p = __expf(v1[7]-mrun1); ps1 += p; hi1.w = f2bf(p);
      lrun0 += ps0; lrun1 += ps1;
      // P[q=l15][key]: lane writes its 4 contiguous keys per half
      *(ushort4*)&Pl[0][l15 * 40 + lg * 4]      = lo0;
      *(ushort4*)&Pl[0][l15 * 40 + 16 + lg * 4] = hi0;
      *(ushort4*)&Pl[1][l15 * 40 + lg * 4]      = lo1;
      *(ushort4*)&Pl[1][l15 * 40 + 16 + lg * 4] = hi1;
    }
    // wave-local LDS RAW: fence compiler ordering + drain DS queue
    asm volatile("s_waitcnt lgkmcnt(0)" ::: "memory");
    __builtin_amdgcn_sched_barrier(0);

    // ---- PV: A = P[q][key] (b128 read), B = V^T fragments shared by both comps
    const s16x8 pa0 = *(const s16x8*)&Pl[0][l15 * 40 + lg * 8];
    const s16x8 pa1 = *(const s16x8*)&Pl[1][l15 * 40 + lg * 8];
    #pragma unroll
    for (int nf = 0; nf < 16; ++nf) {
      const s16x8 vf = *(const s16x8*)(vbase + (size_t)(nf * 16 + l15) * TTOK + kb + lg * 8);
      oacc0[nf] = __builtin_amdgcn_mfma_f32_16x16x32_bf16(pa0, vf, oacc0[nf], 0, 0, 0);
      oacc1[nf] = __builtin_amdgcn_mfma_f32_16x16x32_bf16(pa1, vf, oacc1[nf], 0, 0, 0);
    }
  }

  // ---- finalize row sums (keys were spread over lg groups)
  lrun0 += __shfl_xor(lrun0, 16); lrun0 += __shfl_xor(lrun0, 32);
  lrun1 += __shfl_xor(lrun1, 16); lrun1 += __shfl_xor(lrun1, 32);

  // move 1/l into oacc orientation (lane needs rows lg*4+jj)
  float li0[4], li1[4];
  #pragma unroll
  for (int jj = 0; jj < 4; ++jj) {
    li0[jj] = 1.0f / __shfl(lrun0, lg * 4 + jj);
    li1[jj] = 1.0f / __shfl(lrun1, lg * 4 + jj);
  }

  // ---- combine, RMSNorm over 256, scale, store
  float ss[4] = {0.f, 0.f, 0.f, 0.f};
  #pragma unroll
  for (int nf = 0; nf < 16; ++nf)
    #pragma unroll
    for (int jj = 0; jj < 4; ++jj) {
      const float o = oacc0[nf][jj] * li0[jj] - lam * oacc1[nf][jj] * li1[jj];
      oacc0[nf][jj] = o;
      ss[jj] += o * o;
    }
  #pragma unroll
  for (int jj = 0; jj < 4; ++jj) {
    ss[jj] += __shfl_xor(ss[jj], 1);
    ss[jj] += __shfl_xor(ss[jj], 2);
    ss[jj] += __shfl_xor(ss[jj], 4);
    ss[jj] += __shfl_xor(ss[jj], 8);
    ss[jj] = rsqrtf(ss[jj] * (1.0f / 256.0f) + 1e-5f) * OML;
  }
  #pragma unroll
  for (int nf = 0; nf < 16; ++nf) {
    const int dcol = nf * 16 + l15;
    const float sw = subln[dcol];
    #pragma unroll
    for (int jj = 0; jj < 4; ++jj) {
      const int t = q0 + lg * 4 + jj;
      attn_out[(size_t)t * HIDN + pair * VD + dcol] = f2bf(oacc0[nf][jj] * ss[jj] * sw);
    }
  }
}

extern "C" void kernel_launch(void* const* d_in, const int* in_sizes, int n_in,
                              void* d_out, int out_size, void* d_ws, size_t ws_size,
                              hipStream_t stream) {
  (void)in_sizes; (void)n_in; (void)out_size; (void)ws_size;
  const float* hs     = (const float*)d_in[0];
  const float* wqkv_w = (const float*)d_in[1];
  const float* wqkv_b = (const float*)d_in[2];
  const float* lq1    = (const float*)d_in[3];
  const float* lk1    = (const float*)d_in[4];
  const float* lq2    = (const float*)d_in[5];
  const float* lk2    = (const float*)d_in[6];
  const float* subln  = (const float*)d_in[7];
  const float* out_w  = (const float*)d_in[8];
  const float* out_b  = (const float*)d_in[9];

  // ws layout (bf16): qkv [TTOK][OPD] | V^T [1024][TTOK] | attn_out [TTOK][HIDN]  (~46 MB)
  unsigned short* qkv      = (unsigned short*)d_ws;
  unsigned short* vt       = qkv + (size_t)TTOK * OPD;
  unsigned short* attn_out = vt + (size_t)1024 * TTOK;

  // GEMM1: qkv = hs @ wqkv_w^T + b   (V region diverted to V^T buffer)
  gemm_bt<false, true, true><<<dim3(OPD / 128, TTOK / 128), 256, 0, stream>>>(
      hs, wqkv_w, wqkv_b, qkv, vt, HIDN, HIDN, HIDN, OPD);

  // Attention + combine + RMSNorm -> attn_out (bf16)
  attn_kernel<<<dim3(16, TTOK / 16), 64, 0, stream>>>(
      qkv, vt, lq1, lk1, lq2, lk2, subln, attn_out);

  // GEMM2: out = attn_out @ out_w^T + out_b  (fp32 out)
  gemm_bt<true, false, false><<<dim3(HIDN / 128, TTOK / 128), 256, 0, stream>>>(
      attn_out, out_w, out_b, d_out, nullptr, HIDN, HIDN, HIDN, HIDN);
}

// Round 3
// 550.245 us; speedup vs baseline: 1.5507x; 1.4627x over previous
//
#include <hip/hip_runtime.h>

#define TTOK 2048
#define HIDN 4096
#define OPD  6144
#define DH   128
#define VD   256
#define KOFF 4096
#define VOFF 5120

typedef short  s16x8 __attribute__((ext_vector_type(8)));
typedef unsigned short u16x8 __attribute__((ext_vector_type(8)));
typedef float  fx4   __attribute__((ext_vector_type(4)));

constexpr float LAM_INIT = 0.7455692280263534f;
constexpr float OML      = 1.0f - LAM_INIT;          // (1 - lambda_init)
constexpr float QKSCALE  = 0.08838834764831845f;     // 128^-0.5
constexpr float RESCALE_THR = 8.0f;

__device__ __forceinline__ unsigned short f2bf(float f) {
  unsigned int u = __builtin_bit_cast(unsigned int, f);
  u += 0x7fffu + ((u >> 16) & 1u);   // RNE
  return (unsigned short)(u >> 16);
}

__device__ __forceinline__ void g2l16(const void* gsrc, void* ldst) {
  __builtin_amdgcn_global_load_lds(
      (const __attribute__((address_space(1))) unsigned int*)gsrc,
      (__attribute__((address_space(3))) unsigned int*)ldst, 16, 0, 0);
}

// C[M,N] = A[M,K] * B[N,K]^T + bias.  A: fp32 or bf16 row-major, B: fp32 row-major.
// QKVOUT: Q region (n0<KOFF) -> Cp row-major bf16; K/V regions -> ctt tiled layout:
//   per (kvp, ktile): 16384 elems = [K: cc(32)x key(32)x c8(8)] [V: kc(4)x d(256)x k8(8)]
template<bool ABF16, bool OUTBF16, bool QKVOUT>
__global__ __launch_bounds__(256)
void gemm_bt(const void* __restrict__ Ap, const void* __restrict__ Bp,
             const float* __restrict__ bias, void* __restrict__ Cp,
             unsigned short* __restrict__ ctt,
             int K, int lda, int ldb, int ldc)
{
  __shared__ unsigned short As[128 * 40];
  __shared__ unsigned short Bs[128 * 40];
  const int tid  = threadIdx.x;
  const int lane = tid & 63, wid = tid >> 6;
  const int wr = wid >> 1, wc = wid & 1;       // 2x2 wave grid, 64x64 out each
  const int m0 = blockIdx.y * 128, n0 = blockIdx.x * 128;
  const int l15 = lane & 15, lg = lane >> 4;

  fx4 acc[4][4] = {};

  for (int kt = 0; kt < K; kt += 32) {
    #pragma unroll
    for (int it = 0; it < 2; ++it) {
      const int slot = it * 256 + tid;
      const int row  = slot >> 2;
      const int c8   = (slot & 3) << 3;
      u16x8 va, vb;
      if (ABF16) {
        va = *(const u16x8*)((const unsigned short*)Ap + (size_t)(m0 + row) * lda + kt + c8);
      } else {
        const float* ap = (const float*)Ap + (size_t)(m0 + row) * lda + kt + c8;
        const float4 a0 = *(const float4*)ap;
        const float4 a1 = *(const float4*)(ap + 4);
        va[0]=f2bf(a0.x); va[1]=f2bf(a0.y); va[2]=f2bf(a0.z); va[3]=f2bf(a0.w);
        va[4]=f2bf(a1.x); va[5]=f2bf(a1.y); va[6]=f2bf(a1.z); va[7]=f2bf(a1.w);
      }
      {
        const float* bp = (const float*)Bp + (size_t)(n0 + row) * ldb + kt + c8;
        const float4 b0 = *(const float4*)bp;
        const float4 b1 = *(const float4*)(bp + 4);
        vb[0]=f2bf(b0.x); vb[1]=f2bf(b0.y); vb[2]=f2bf(b0.z); vb[3]=f2bf(b0.w);
        vb[4]=f2bf(b1.x); vb[5]=f2bf(b1.y); vb[6]=f2bf(b1.z); vb[7]=f2bf(b1.w);
      }
      *(u16x8*)&As[row * 40 + c8] = va;
      *(u16x8*)&Bs[row * 40 + c8] = vb;
    }
    __syncthreads();
    s16x8 af[4], bf[4];
    #pragma unroll
    for (int i = 0; i < 4; ++i) {
      af[i] = *(const s16x8*)&As[(wr * 64 + i * 16 + l15) * 40 + lg * 8];
      bf[i] = *(const s16x8*)&Bs[(wc * 64 + i * 16 + l15) * 40 + lg * 8];
    }
    #pragma unroll
    for (int mi = 0; mi < 4; ++mi)
      #pragma unroll
      for (int ni = 0; ni < 4; ++ni)
        acc[mi][ni] = __builtin_amdgcn_mfma_f32_16x16x32_bf16(af[mi], bf[ni], acc[mi][ni], 0, 0, 0);
    __syncthreads();
  }

  const int r0 = m0 + wr * 64;
  const int c0 = n0 + wc * 64;
  if (QKVOUT && n0 >= VOFF) {
    // V region -> ctt tiled, ushort4 over 4 consecutive keys
    #pragma unroll
    for (int mi = 0; mi < 4; ++mi)
      #pragma unroll
      for (int ni = 0; ni < 4; ++ni) {
        const int col = c0 + ni * 16 + l15;
        const float bv = bias[col];
        const fx4 a = acc[mi][ni];
        ushort4 pk;
        pk.x = f2bf(a[0] + bv); pk.y = f2bf(a[1] + bv);
        pk.z = f2bf(a[2] + bv); pk.w = f2bf(a[3] + bv);
        const int d   = col - VOFF;
        const int kvp = d >> 8, dw = d & 255;
        const int row0 = r0 + mi * 16 + lg * 4;      // key
        const int kt2 = row0 >> 5, kk = row0 & 31;
        const int kc = kk >> 3, k8 = kk & 7;
        *(ushort4*)&ctt[(size_t)kvp * 1048576 + (size_t)kt2 * 16384 + 8192
                        + kc * 2048 + dw * 8 + k8] = pk;
      }
  } else if (QKVOUT && n0 >= KOFF) {
    // K region -> ctt tiled, scalar stores
    #pragma unroll
    for (int mi = 0; mi < 4; ++mi)
      #pragma unroll
      for (int ni = 0; ni < 4; ++ni) {
        const int ccol = c0 + ni * 16 + l15 - KOFF;  // 0..1023
        const float bv = bias[c0 + ni * 16 + l15];
        const int kvp = ccol >> 8, cw = ccol & 255;
        const int cc = cw >> 3, c8 = cw & 7;
        const fx4 a = acc[mi][ni];
        #pragma unroll
        for (int jj = 0; jj < 4; ++jj) {
          const int row = r0 + mi * 16 + lg * 4 + jj;   // key
          const int kt2 = row >> 5, kk = row & 31;
          ctt[(size_t)kvp * 1048576 + (size_t)kt2 * 16384 + cc * 256 + kk * 8 + c8]
              = f2bf(a[jj] + bv);
        }
      }
  } else {
    #pragma unroll
    for (int mi = 0; mi < 4; ++mi)
      #pragma unroll
      for (int ni = 0; ni < 4; ++ni) {
        const int col = c0 + ni * 16 + l15;
        const float bv = bias[col];
        const fx4 a = acc[mi][ni];
        #pragma unroll
        for (int jj = 0; jj < 4; ++jj) {
          const int row = r0 + mi * 16 + lg * 4 + jj;
          const float v = a[jj] + bv;
          if (OUTBF16) ((unsigned short*)Cp)[(size_t)row * ldc + col] = f2bf(v);
          else         ((float*)Cp)[(size_t)row * ldc + col] = v;
        }
      }
  }
}

// Block = (pair, 64 q-rows), 4 waves (16 rows each, both diff components).
// K/V staged per 32-key tile via global_load_lds from the tile-contiguous ctt,
// double-buffered, ONE barrier per tile. All fragment ds_reads conflict-free.
__global__ __launch_bounds__(256, 2)
void attn_kernel(const unsigned short* __restrict__ qq,    // [TTOK][HIDN] bf16 Q
                 const unsigned short* __restrict__ ctt,   // tiled K/V
                 const float* __restrict__ lq1, const float* __restrict__ lk1,
                 const float* __restrict__ lq2, const float* __restrict__ lk2,
                 const float* __restrict__ subln,
                 unsigned short* __restrict__ attn_out)    // [TTOK][HIDN] bf16
{
  __shared__ __align__(16) unsigned short Sb[2][16384];    // [K 16KB][V 16KB]
  __shared__ __align__(16) unsigned short Pl[4][2][640];
  const int tid = threadIdx.x;
  const int lane = tid & 63, w = tid >> 6;
  const int l15 = lane & 15, lg = lane >> 4;

  // block decode: kvp -> XCD affinity, heavy q-blocks first
  const int bid = blockIdx.x;
  const int g = bid & 7, s = bid >> 3;
  const int kvp  = g >> 1;
  const int pair = kvp * 4 + (s & 3);
  const int qb   = 31 - ((s >> 2) << 1) - (g & 1);
  const int q0b  = qb * 64;
  const int q0w  = q0b + w * 16;
  const int nt   = 2 * qb + 2;

  const unsigned short* cbase = ctt + (size_t)kvp * 1048576;

  // stage tile kt (32KB linear) into Sb[buf]: 8 x global_load_lds(16B) per wave
  auto stage = [&](int kt, int buf) {
    const unsigned short* src = cbase + (size_t)kt * 16384;
    const int off = w * 512 + lane * 8;
    #pragma unroll
    for (int i = 0; i < 8; ++i) {
      const int o = i * 2048 + off;
      g2l16(src + o, &Sb[buf][o]);
    }
  };

  stage(0, 0);

  // lambda via wave-parallel dot
  float a1 = lq1[lane] * lk1[lane] + lq1[lane + 64] * lk1[lane + 64];
  float a2 = lq2[lane] * lk2[lane] + lq2[lane + 64] * lk2[lane + 64];
  #pragma unroll
  for (int sft = 1; sft < 64; sft <<= 1) { a1 += __shfl_xor(a1, sft); a2 += __shfl_xor(a2, sft); }
  const float lam = __expf(a1) - __expf(a2) + LAM_INIT;

  // Q fragments
  s16x8 qf0[4], qf1[4];
  {
    const unsigned short* qbp = qq + (size_t)(q0w + l15) * HIDN + pair * VD + lg * 8;
    #pragma unroll
    for (int kf = 0; kf < 4; ++kf) {
      qf0[kf] = *(const s16x8*)(qbp + kf * 32);
      qf1[kf] = *(const s16x8*)(qbp + DH + kf * 32);
    }
  }

  float mrun0 = -1e30f, mrun1 = -1e30f;
  float lrun0 = 0.f, lrun1 = 0.f;
  fx4 oacc0[16] = {}, oacc1[16] = {};
  unsigned short* pl0 = &Pl[w][0][0];
  unsigned short* pl1 = &Pl[w][1][0];
  const int q = q0w + l15;
  const int qmax = q0w + 15;

  for (int t = 0; t < nt; ++t) {
    __syncthreads();                      // stage(t) visible; buf[(t+1)&1] free
    if (t + 1 < nt) stage(t + 1, (t + 1) & 1);
    const int kb = t * 32;
    if (kb > qmax) continue;              // wave-uniform; still hits barrier next iter
    const unsigned short* Kl = Sb[t & 1];
    const unsigned short* Vl = Sb[t & 1] + 8192;

    // ---- QK^T swapped: S^T[key][q]
    fx4 s00 = {0,0,0,0}, s01 = {0,0,0,0}, s10 = {0,0,0,0}, s11 = {0,0,0,0};
    #pragma unroll
    for (int kf = 0; kf < 4; ++kf) {
      const int cc0 = kf * 4 + lg;        // comp0 chunks
      const int cc1 = 16 + kf * 4 + lg;   // comp1 chunks
      const s16x8 k00 = *(const s16x8*)&Kl[cc0 * 256 + l15 * 8];
      const s16x8 k01 = *(const s16x8*)&Kl[cc0 * 256 + (16 + l15) * 8];
      const s16x8 k10 = *(const s16x8*)&Kl[cc1 * 256 + l15 * 8];
      const s16x8 k11 = *(const s16x8*)&Kl[cc1 * 256 + (16 + l15) * 8];
      s00 = __builtin_amdgcn_mfma_f32_16x16x32_bf16(k00, qf0[kf], s00, 0, 0, 0);
      s01 = __builtin_amdgcn_mfma_f32_16x16x32_bf16(k01, qf0[kf], s01, 0, 0, 0);
      s10 = __builtin_amdgcn_mfma_f32_16x16x32_bf16(k10, qf1[kf], s10, 0, 0, 0);
      s11 = __builtin_amdgcn_mfma_f32_16x16x32_bf16(k11, qf1[kf], s11, 0, 0, 0);
    }

    // ---- mask + scale
    float v0[8], v1[8];
    #pragma unroll
    for (int j = 0; j < 4; ++j) {
      const int klo = kb + lg * 4 + j, khi = klo + 16;
      v0[j]     = (klo <= q) ? s00[j] * QKSCALE : -1e30f;
      v0[4 + j] = (khi <= q) ? s01[j] * QKSCALE : -1e30f;
      v1[j]     = (klo <= q) ? s10[j] * QKSCALE : -1e30f;
      v1[4 + j] = (khi <= q) ? s11[j] * QKSCALE : -1e30f;
    }
    // ---- tile max per comp
    float tm0 = fmaxf(fmaxf(fmaxf(v0[0],v0[1]),fmaxf(v0[2],v0[3])),
                      fmaxf(fmaxf(v0[4],v0[5]),fmaxf(v0[6],v0[7])));
    float tm1 = fmaxf(fmaxf(fmaxf(v1[0],v1[1]),fmaxf(v1[2],v1[3])),
                      fmaxf(fmaxf(v1[4],v1[5]),fmaxf(v1[6],v1[7])));
    tm0 = fmaxf(tm0, __shfl_xor(tm0, 16)); tm0 = fmaxf(tm0, __shfl_xor(tm0, 32));
    tm1 = fmaxf(tm1, __shfl_xor(tm1, 16)); tm1 = fmaxf(tm1, __shfl_xor(tm1, 32));

    // ---- defer-max rescale (rare)
    const bool need = (tm0 > mrun0 + RESCALE_THR) || (tm1 > mrun1 + RESCALE_THR);
    if (__any(need)) {
      const float mn0 = fmaxf(mrun0, tm0), mn1 = fmaxf(mrun1, tm1);
      const float fac0 = __expf(mrun0 - mn0), fac1 = __expf(mrun1 - mn1);
      mrun0 = mn0; mrun1 = mn1;
      lrun0 *= fac0; lrun1 *= fac1;
      #pragma unroll
      for (int jj = 0; jj < 4; ++jj) {
        const float fr0 = __shfl(fac0, lg * 4 + jj);
        const float fr1 = __shfl(fac1, lg * 4 + jj);
        #pragma unroll
        for (int nf = 0; nf < 16; ++nf) { oacc0[nf][jj] *= fr0; oacc1[nf][jj] *= fr1; }
      }
    }

    // ---- P = exp(v - mrun), pack bf16 -> per-wave LDS transpose
    {
      float ps0 = 0.f, ps1 = 0.f;
      ushort4 lo0, hi0, lo1, hi1;
      float p;
      p = __expf(v0[0]-mrun0); ps0 += p; lo0.x = f2bf(p);
      p = __expf(v0[1]-mrun0); ps0 += p; lo0.y = f2bf(p);
      p = __expf(v0[2]-mrun0); ps0 += p; lo0.z = f2bf(p);
      p = __expf(v0[3]-mrun0); ps0 += p; lo0.w = f2bf(p);
      p = __expf(v0[4]-mrun0); ps0 += p; hi0.x = f2bf(p);
      p = __expf(v0[5]-mrun0); ps0 += p; hi0.y = f2bf(p);
      p = __expf(v0[6]-mrun0); ps0 += p; hi0.z = f2bf(p);
      p = __expf(v0[7]-mrun0); ps0 += p; hi0.w = f2bf(p);
      p = __expf(v1[0]-mrun1); ps1 += p; lo1.x = f2bf(p);
      p = __expf(v1[1]-mrun1); ps1 += p; lo1.y = f2bf(p);
      p = __expf(v1[2]-mrun1); ps1 += p; lo1.z = f2bf(p);
      p = __expf(v1[3]-mrun1); ps1 += p; lo1.w = f2bf(p);
      p = __expf(v1[4]-mrun1); ps1 += p; hi1.x = f2bf(p);
      p = __expf(v1[5]-mrun1); ps1 += p; hi1.y = f2bf(p);
      p = __expf(v1[6]-mrun1); ps1 += p; hi1.z = f2bf(p);
      p = __expf(v1[7]-mrun1); ps1 += p; hi1.w = f2bf(p);
      lrun0 += ps0; lrun1 += ps1;
      *(ushort4*)&pl0[l15 * 40 + lg * 4]      = lo0;
      *(ushort4*)&pl0[l15 * 40 + 16 + lg * 4] = hi0;
      *(ushort4*)&pl1[l15 * 40 + lg * 4]      = lo1;
      *(ushort4*)&pl1[l15 * 40 + 16 + lg * 4] = hi1;
    }
    asm volatile("s_waitcnt lgkmcnt(0)" ::: "memory");
    __builtin_amdgcn_sched_barrier(0);

    // ---- PV from LDS V tile (conflict-free layout)
    const s16x8 pa0 = *(const s16x8*)&pl0[l15 * 40 + lg * 8];
    const s16x8 pa1 = *(const s16x8*)&pl1[l15 * 40 + lg * 8];
    #pragma unroll
    for (int nf = 0; nf < 16; ++nf) {
      const s16x8 vf = *(const s16x8*)&Vl[lg * 2048 + (nf * 16 + l15) * 8];
      oacc0[nf] = __builtin_amdgcn_mfma_f32_16x16x32_bf16(pa0, vf, oacc0[nf], 0, 0, 0);
      oacc1[nf] = __builtin_amdgcn_mfma_f32_16x16x32_bf16(pa1, vf, oacc1[nf], 0, 0, 0);
    }
  }

  // ---- finalize row sums
  lrun0 += __shfl_xor(lrun0, 16); lrun0 += __shfl_xor(lrun0, 32);
  lrun1 += __shfl_xor(lrun1, 16); lrun1 += __shfl_xor(lrun1, 32);

  float li0[4], li1[4];
  #pragma unroll
  for (int jj = 0; jj < 4; ++jj) {
    li0[jj] = 1.0f / __shfl(lrun0, lg * 4 + jj);
    li1[jj] = 1.0f / __shfl(lrun1, lg * 4 + jj);
  }

  // ---- combine, RMSNorm over 256, scale, store
  float ss[4] = {0.f, 0.f, 0.f, 0.f};
  #pragma unroll
  for (int nf = 0; nf < 16; ++nf)
    #pragma unroll
    for (int jj = 0; jj < 4; ++jj) {
      const float o = oacc0[nf][jj] * li0[jj] - lam * oacc1[nf][jj] * li1[jj];
      oacc0[nf][jj] = o;
      ss[jj] += o * o;
    }
  #pragma unroll
  for (int jj = 0; jj < 4; ++jj) {
    ss[jj] += __shfl_xor(ss[jj], 1);
    ss[jj] += __shfl_xor(ss[jj], 2);
    ss[jj] += __shfl_xor(ss[jj], 4);
    ss[jj] += __shfl_xor(ss[jj], 8);
    ss[jj] = rsqrtf(ss[jj] * (1.0f / 256.0f) + 1e-5f) * OML;
  }
  #pragma unroll
  for (int nf = 0; nf < 16; ++nf) {
    const int dcol = nf * 16 + l15;
    const float sw = subln[dcol];
    #pragma unroll
    for (int jj = 0; jj < 4; ++jj) {
      const int t = q0w + lg * 4 + jj;
      attn_out[(size_t)t * HIDN + pair * VD + dcol] = f2bf(oacc0[nf][jj] * ss[jj] * sw);
    }
  }
}

extern "C" void kernel_launch(void* const* d_in, const int* in_sizes, int n_in,
                              void* d_out, int out_size, void* d_ws, size_t ws_size,
                              hipStream_t stream) {
  (void)in_sizes; (void)n_in; (void)out_size; (void)ws_size;
  const float* hs     = (const float*)d_in[0];
  const float* wqkv_w = (const float*)d_in[1];
  const float* wqkv_b = (const float*)d_in[2];
  const float* lq1    = (const float*)d_in[3];
  const float* lk1    = (const float*)d_in[4];
  const float* lq2    = (const float*)d_in[5];
  const float* lk2    = (const float*)d_in[6];
  const float* subln  = (const float*)d_in[7];
  const float* out_w  = (const float*)d_in[8];
  const float* out_b  = (const float*)d_in[9];

  // ws (bf16): qq [2048][4096] | ctt 4*1048576 (tiled K/V) | attn_out [2048][4096]  (~42 MB)
  unsigned short* qq       = (unsigned short*)d_ws;
  unsigned short* ctt      = qq + (size_t)TTOK * HIDN;
  unsigned short* attn_out = ctt + (size_t)4 * 1048576;

  // GEMM1: Q -> qq row-major; K/V -> ctt tiled
  gemm_bt<false, true, true><<<dim3(OPD / 128, TTOK / 128), 256, 0, stream>>>(
      hs, wqkv_w, wqkv_b, qq, ctt, HIDN, HIDN, HIDN, HIDN);

  // Attention + combine + RMSNorm -> attn_out (bf16)
  attn_kernel<<<dim3(512), 256, 0, stream>>>(
      qq, ctt, lq1, lk1, lq2, lk2, subln, attn_out);

  // GEMM2: out = attn_out @ out_w^T + out_b  (fp32 out)
  gemm_bt<true, false, false><<<dim3(HIDN / 128, TTOK / 128), 256, 0, stream>>>(
      attn_out, out_w, out_b, d_out, nullptr, HIDN, HIDN, HIDN, HIDN);
}

// Round 4
// 440.462 us; speedup vs baseline: 1.9372x; 1.2492x over previous
//
#include <hip/hip_runtime.h>

#define TTOK 2048
#define HIDN 4096
#define OPD  6144
#define DH   128
#define VD   256
#define KOFF 4096
#define VOFF 5120

typedef short  s16x8 __attribute__((ext_vector_type(8)));
typedef unsigned short u16x8 __attribute__((ext_vector_type(8)));
typedef float  fx4   __attribute__((ext_vector_type(4)));

constexpr float LAM_INIT = 0.7455692280263534f;
constexpr float OML      = 1.0f - LAM_INIT;          // (1 - lambda_init)
constexpr float QKSCALE  = 0.08838834764831845f;     // 128^-0.5
constexpr float RESCALE_THR = 8.0f;

__device__ __forceinline__ unsigned short f2bf(float f) {
  unsigned int u = __builtin_bit_cast(unsigned int, f);
  u += 0x7fffu + ((u >> 16) & 1u);   // RNE
  return (unsigned short)(u >> 16);
}

__device__ __forceinline__ void g2l16(const void* gsrc, void* ldst) {
  __builtin_amdgcn_global_load_lds(
      (const __attribute__((address_space(1))) unsigned int*)gsrc,
      (__attribute__((address_space(3))) unsigned int*)ldst, 16, 0, 0);
}

// fp32 -> bf16 bulk convert, 3 tensors, 2048 elems/block (all sizes % 2048 == 0)
__global__ __launch_bounds__(256)
void cvt3(const float* __restrict__ s0, unsigned short* __restrict__ d0, int nb0,
          const float* __restrict__ s1, unsigned short* __restrict__ d1, int nb1,
          const float* __restrict__ s2, unsigned short* __restrict__ d2)
{
  const int b = blockIdx.x;
  const float* s; unsigned short* d; int base;
  if (b < nb0)            { s = s0; d = d0; base = b << 11; }
  else if (b < nb0 + nb1) { s = s1; d = d1; base = (b - nb0) << 11; }
  else                    { s = s2; d = d2; base = (b - nb0 - nb1) << 11; }
  const int i = base + (int)threadIdx.x * 8;
  const float4 a0 = *(const float4*)(s + i);
  const float4 a1 = *(const float4*)(s + i + 4);
  u16x8 v;
  v[0]=f2bf(a0.x); v[1]=f2bf(a0.y); v[2]=f2bf(a0.z); v[3]=f2bf(a0.w);
  v[4]=f2bf(a1.x); v[5]=f2bf(a1.y); v[6]=f2bf(a1.z); v[7]=f2bf(a1.w);
  *(u16x8*)(d + i) = v;
}

// C[M,N] = A[M,K] * B[N,K]^T + bias.  A,B bf16 row-major. m97 structure:
// global_load_lds(16B) staging into linear [128][32] LDS, 2 barriers/K-step.
// QKVOUT: Q region -> Cp row-major bf16; K/V regions -> ctt tiled layout:
//   per (kvp, ktile): 16384 elems = [K: cc(32)x key(32)x c8(8)] [V: kc(4)x d(256)x k8(8)]
template<bool QKVOUT, bool OUTBF16>
__global__ __launch_bounds__(256)
void gemm_bf16(const unsigned short* __restrict__ A, const unsigned short* __restrict__ B,
               const float* __restrict__ bias, void* __restrict__ Cp,
               unsigned short* __restrict__ ctt, int K, int lda, int ldb, int ldc)
{
  __shared__ __align__(16) unsigned short As[128 * 32];
  __shared__ __align__(16) unsigned short Bs[128 * 32];
  const int tid  = threadIdx.x;
  const int lane = tid & 63, wid = tid >> 6;
  const int wr = wid >> 1, wc = wid & 1;       // 2x2 wave grid, 64x64 out each
  const int m0 = blockIdx.y * 128, n0 = blockIdx.x * 128;
  const int l15 = lane & 15, lg = lane >> 4;
  const int c8 = (tid & 3) << 3;

  fx4 acc[4][4] = {};

  for (int kt = 0; kt < K; kt += 32) {
    #pragma unroll
    for (int it = 0; it < 2; ++it) {
      const int s2  = it * 256 + tid;
      const int row = s2 >> 2;
      g2l16(A + (size_t)(m0 + row) * lda + kt + c8, &As[s2 * 8]);
      g2l16(B + (size_t)(n0 + row) * ldb + kt + c8, &Bs[s2 * 8]);
    }
    __syncthreads();                     // drains vmcnt -> staged tile visible
    s16x8 af[4], bf[4];
    #pragma unroll
    for (int i = 0; i < 4; ++i) {
      af[i] = *(const s16x8*)&As[(wr * 64 + i * 16 + l15) * 32 + lg * 8];
      bf[i] = *(const s16x8*)&Bs[(wc * 64 + i * 16 + l15) * 32 + lg * 8];
    }
    #pragma unroll
    for (int mi = 0; mi < 4; ++mi)
      #pragma unroll
      for (int ni = 0; ni < 4; ++ni)
        acc[mi][ni] = __builtin_amdgcn_mfma_f32_16x16x32_bf16(af[mi], bf[ni], acc[mi][ni], 0, 0, 0);
    __syncthreads();                     // all reads done before next stage
  }

  const int r0 = m0 + wr * 64;
  const int c0 = n0 + wc * 64;
  if (QKVOUT && n0 >= VOFF) {
    // V region -> ctt tiled, ushort4 over 4 consecutive keys
    #pragma unroll
    for (int mi = 0; mi < 4; ++mi)
      #pragma unroll
      for (int ni = 0; ni < 4; ++ni) {
        const int col = c0 + ni * 16 + l15;
        const float bv = bias[col];
        const fx4 a = acc[mi][ni];
        ushort4 pk;
        pk.x = f2bf(a[0] + bv); pk.y = f2bf(a[1] + bv);
        pk.z = f2bf(a[2] + bv); pk.w = f2bf(a[3] + bv);
        const int d   = col - VOFF;
        const int kvp = d >> 8, dw = d & 255;
        const int row0 = r0 + mi * 16 + lg * 4;      // key
        const int kt2 = row0 >> 5, kk = row0 & 31;
        const int kc = kk >> 3, k8 = kk & 7;
        *(ushort4*)&ctt[(size_t)kvp * 1048576 + (size_t)kt2 * 16384 + 8192
                        + kc * 2048 + dw * 8 + k8] = pk;
      }
  } else if (QKVOUT && n0 >= KOFF) {
    // K region -> ctt tiled, scalar stores
    #pragma unroll
    for (int mi = 0; mi < 4; ++mi)
      #pragma unroll
      for (int ni = 0; ni < 4; ++ni) {
        const int ccol = c0 + ni * 16 + l15 - KOFF;  // 0..1023
        const float bv = bias[c0 + ni * 16 + l15];
        const int kvp = ccol >> 8, cw = ccol & 255;
        const int cc = cw >> 3, cb = cw & 7;
        const fx4 a = acc[mi][ni];
        #pragma unroll
        for (int jj = 0; jj < 4; ++jj) {
          const int row = r0 + mi * 16 + lg * 4 + jj;   // key
          const int kt2 = row >> 5, kk = row & 31;
          ctt[(size_t)kvp * 1048576 + (size_t)kt2 * 16384 + cc * 256 + kk * 8 + cb]
              = f2bf(a[jj] + bv);
        }
      }
  } else {
    #pragma unroll
    for (int mi = 0; mi < 4; ++mi)
      #pragma unroll
      for (int ni = 0; ni < 4; ++ni) {
        const int col = c0 + ni * 16 + l15;
        const float bv = bias[col];
        const fx4 a = acc[mi][ni];
        #pragma unroll
        for (int jj = 0; jj < 4; ++jj) {
          const int row = r0 + mi * 16 + lg * 4 + jj;
          const float v = a[jj] + bv;
          if (OUTBF16) ((unsigned short*)Cp)[(size_t)row * ldc + col] = f2bf(v);
          else         ((float*)Cp)[(size_t)row * ldc + col] = v;
        }
      }
  }
}

// Block = (pair, 64 q-rows), 4 waves (16 rows each, both diff components).
// K/V staged per 32-key tile via global_load_lds from the tile-contiguous ctt,
// double-buffered, ONE barrier per tile. All fragment ds_reads conflict-free.
__global__ __launch_bounds__(256, 2)
void attn_kernel(const unsigned short* __restrict__ qq,    // [TTOK][HIDN] bf16 Q
                 const unsigned short* __restrict__ ctt,   // tiled K/V
                 const float* __restrict__ lq1, const float* __restrict__ lk1,
                 const float* __restrict__ lq2, const float* __restrict__ lk2,
                 const float* __restrict__ subln,
                 unsigned short* __restrict__ attn_out)    // [TTOK][HIDN] bf16
{
  __shared__ __align__(16) unsigned short Sb[2][16384];    // [K 16KB][V 16KB]
  __shared__ __align__(16) unsigned short Pl[4][2][640];
  const int tid = threadIdx.x;
  const int lane = tid & 63, w = tid >> 6;
  const int l15 = lane & 15, lg = lane >> 4;

  // block decode: kvp -> XCD affinity, heavy q-blocks first
  const int bid = blockIdx.x;
  const int g = bid & 7, s = bid >> 3;
  const int kvp  = g >> 1;
  const int pair = kvp * 4 + (s & 3);
  const int qb   = 31 - ((s >> 2) << 1) - (g & 1);
  const int q0b  = qb * 64;
  const int q0w  = q0b + w * 16;
  const int nt   = 2 * qb + 2;

  const unsigned short* cbase = ctt + (size_t)kvp * 1048576;

  // stage tile kt (32KB linear) into Sb[buf]: 8 x global_load_lds(16B) per wave
  auto stage = [&](int kt, int buf) {
    const unsigned short* src = cbase + (size_t)kt * 16384;
    const int off = w * 512 + lane * 8;
    #pragma unroll
    for (int i = 0; i < 8; ++i) {
      const int o = i * 2048 + off;
      g2l16(src + o, &Sb[buf][o]);
    }
  };

  stage(0, 0);

  // lambda via wave-parallel dot
  float a1 = lq1[lane] * lk1[lane] + lq1[lane + 64] * lk1[lane + 64];
  float a2 = lq2[lane] * lk2[lane] + lq2[lane + 64] * lk2[lane + 64];
  #pragma unroll
  for (int sft = 1; sft < 64; sft <<= 1) { a1 += __shfl_xor(a1, sft); a2 += __shfl_xor(a2, sft); }
  const float lam = __expf(a1) - __expf(a2) + LAM_INIT;

  // Q fragments
  s16x8 qf0[4], qf1[4];
  {
    const unsigned short* qbp = qq + (size_t)(q0w + l15) * HIDN + pair * VD + lg * 8;
    #pragma unroll
    for (int kf = 0; kf < 4; ++kf) {
      qf0[kf] = *(const s16x8*)(qbp + kf * 32);
      qf1[kf] = *(const s16x8*)(qbp + DH + kf * 32);
    }
  }

  float mrun0 = -1e30f, mrun1 = -1e30f;
  float lrun0 = 0.f, lrun1 = 0.f;
  fx4 oacc0[16] = {}, oacc1[16] = {};
  unsigned short* pl0 = &Pl[w][0][0];
  unsigned short* pl1 = &Pl[w][1][0];
  const int q = q0w + l15;
  const int qmax = q0w + 15;

  for (int t = 0; t < nt; ++t) {
    __syncthreads();                      // stage(t) visible; buf[(t+1)&1] free
    if (t + 1 < nt) stage(t + 1, (t + 1) & 1);
    const int kb = t * 32;
    if (kb > qmax) continue;              // wave-uniform; still hits barrier next iter
    const unsigned short* Kl = Sb[t & 1];
    const unsigned short* Vl = Sb[t & 1] + 8192;

    // ---- QK^T swapped: S^T[key][q]
    fx4 s00 = {0,0,0,0}, s01 = {0,0,0,0}, s10 = {0,0,0,0}, s11 = {0,0,0,0};
    #pragma unroll
    for (int kf = 0; kf < 4; ++kf) {
      const int cc0 = kf * 4 + lg;        // comp0 chunks
      const int cc1 = 16 + kf * 4 + lg;   // comp1 chunks
      const s16x8 k00 = *(const s16x8*)&Kl[cc0 * 256 + l15 * 8];
      const s16x8 k01 = *(const s16x8*)&Kl[cc0 * 256 + (16 + l15) * 8];
      const s16x8 k10 = *(const s16x8*)&Kl[cc1 * 256 + l15 * 8];
      const s16x8 k11 = *(const s16x8*)&Kl[cc1 * 256 + (16 + l15) * 8];
      s00 = __builtin_amdgcn_mfma_f32_16x16x32_bf16(k00, qf0[kf], s00, 0, 0, 0);
      s01 = __builtin_amdgcn_mfma_f32_16x16x32_bf16(k01, qf0[kf], s01, 0, 0, 0);
      s10 = __builtin_amdgcn_mfma_f32_16x16x32_bf16(k10, qf1[kf], s10, 0, 0, 0);
      s11 = __builtin_amdgcn_mfma_f32_16x16x32_bf16(k11, qf1[kf], s11, 0, 0, 0);
    }

    // ---- mask + scale
    float v0[8], v1[8];
    #pragma unroll
    for (int j = 0; j < 4; ++j) {
      const int klo = kb + lg * 4 + j, khi = klo + 16;
      v0[j]     = (klo <= q) ? s00[j] * QKSCALE : -1e30f;
      v0[4 + j] = (khi <= q) ? s01[j] * QKSCALE : -1e30f;
      v1[j]     = (klo <= q) ? s10[j] * QKSCALE : -1e30f;
      v1[4 + j] = (khi <= q) ? s11[j] * QKSCALE : -1e30f;
    }
    // ---- tile max per comp
    float tm0 = fmaxf(fmaxf(fmaxf(v0[0],v0[1]),fmaxf(v0[2],v0[3])),
                      fmaxf(fmaxf(v0[4],v0[5]),fmaxf(v0[6],v0[7])));
    float tm1 = fmaxf(fmaxf(fmaxf(v1[0],v1[1]),fmaxf(v1[2],v1[3])),
                      fmaxf(fmaxf(v1[4],v1[5]),fmaxf(v1[6],v1[7])));
    tm0 = fmaxf(tm0, __shfl_xor(tm0, 16)); tm0 = fmaxf(tm0, __shfl_xor(tm0, 32));
    tm1 = fmaxf(tm1, __shfl_xor(tm1, 16)); tm1 = fmaxf(tm1, __shfl_xor(tm1, 32));

    // ---- defer-max rescale (rare)
    const bool need = (tm0 > mrun0 + RESCALE_THR) || (tm1 > mrun1 + RESCALE_THR);
    if (__any(need)) {
      const float mn0 = fmaxf(mrun0, tm0), mn1 = fmaxf(mrun1, tm1);
      const float fac0 = __expf(mrun0 - mn0), fac1 = __expf(mrun1 - mn1);
      mrun0 = mn0; mrun1 = mn1;
      lrun0 *= fac0; lrun1 *= fac1;
      #pragma unroll
      for (int jj = 0; jj < 4; ++jj) {
        const float fr0 = __shfl(fac0, lg * 4 + jj);
        const float fr1 = __shfl(fac1, lg * 4 + jj);
        #pragma unroll
        for (int nf = 0; nf < 16; ++nf) { oacc0[nf][jj] *= fr0; oacc1[nf][jj] *= fr1; }
      }
    }

    // ---- P = exp(v - mrun), pack bf16 -> per-wave LDS transpose
    {
      float ps0 = 0.f, ps1 = 0.f;
      ushort4 lo0, hi0, lo1, hi1;
      float p;
      p = __expf(v0[0]-mrun0); ps0 += p; lo0.x = f2bf(p);
      p = __expf(v0[1]-mrun0); ps0 += p; lo0.y = f2bf(p);
      p = __expf(v0[2]-mrun0); ps0 += p; lo0.z = f2bf(p);
      p = __expf(v0[3]-mrun0); ps0 += p; lo0.w = f2bf(p);
      p = __expf(v0[4]-mrun0); ps0 += p; hi0.x = f2bf(p);
      p = __expf(v0[5]-mrun0); ps0 += p; hi0.y = f2bf(p);
      p = __expf(v0[6]-mrun0); ps0 += p; hi0.z = f2bf(p);
      p = __expf(v0[7]-mrun0); ps0 += p; hi0.w = f2bf(p);
      p = __expf(v1[0]-mrun1); ps1 += p; lo1.x = f2bf(p);
      p = __expf(v1[1]-mrun1); ps1 += p; lo1.y = f2bf(p);
      p = __expf(v1[2]-mrun1); ps1 += p; lo1.z = f2bf(p);
      p = __expf(v1[3]-mrun1); ps1 += p; lo1.w = f2bf(p);
      p = __expf(v1[4]-mrun1); ps1 += p; hi1.x = f2bf(p);
      p = __expf(v1[5]-mrun1); ps1 += p; hi1.y = f2bf(p);
      p = __expf(v1[6]-mrun1); ps1 += p; hi1.z = f2bf(p);
      p = __expf(v1[7]-mrun1); ps1 += p; hi1.w = f2bf(p);
      lrun0 += ps0; lrun1 += ps1;
      *(ushort4*)&pl0[l15 * 40 + lg * 4]      = lo0;
      *(ushort4*)&pl0[l15 * 40 + 16 + lg * 4] = hi0;
      *(ushort4*)&pl1[l15 * 40 + lg * 4]      = lo1;
      *(ushort4*)&pl1[l15 * 40 + 16 + lg * 4] = hi1;
    }
    asm volatile("s_waitcnt lgkmcnt(0)" ::: "memory");
    __builtin_amdgcn_sched_barrier(0);

    // ---- PV from LDS V tile (conflict-free layout)
    const s16x8 pa0 = *(const s16x8*)&pl0[l15 * 40 + lg * 8];
    const s16x8 pa1 = *(const s16x8*)&pl1[l15 * 40 + lg * 8];
    #pragma unroll
    for (int nf = 0; nf < 16; ++nf) {
      const s16x8 vf = *(const s16x8*)&Vl[lg * 2048 + (nf * 16 + l15) * 8];
      oacc0[nf] = __builtin_amdgcn_mfma_f32_16x16x32_bf16(pa0, vf, oacc0[nf], 0, 0, 0);
      oacc1[nf] = __builtin_amdgcn_mfma_f32_16x16x32_bf16(pa1, vf, oacc1[nf], 0, 0, 0);
    }
  }

  // ---- finalize row sums
  lrun0 += __shfl_xor(lrun0, 16); lrun0 += __shfl_xor(lrun0, 32);
  lrun1 += __shfl_xor(lrun1, 16); lrun1 += __shfl_xor(lrun1, 32);

  float li0[4], li1[4];
  #pragma unroll
  for (int jj = 0; jj < 4; ++jj) {
    li0[jj] = 1.0f / __shfl(lrun0, lg * 4 + jj);
    li1[jj] = 1.0f / __shfl(lrun1, lg * 4 + jj);
  }

  // ---- combine, RMSNorm over 256, scale, store
  float ss[4] = {0.f, 0.f, 0.f, 0.f};
  #pragma unroll
  for (int nf = 0; nf < 16; ++nf)
    #pragma unroll
    for (int jj = 0; jj < 4; ++jj) {
      const float o = oacc0[nf][jj] * li0[jj] - lam * oacc1[nf][jj] * li1[jj];
      oacc0[nf][jj] = o;
      ss[jj] += o * o;
    }
  #pragma unroll
  for (int jj = 0; jj < 4; ++jj) {
    ss[jj] += __shfl_xor(ss[jj], 1);
    ss[jj] += __shfl_xor(ss[jj], 2);
    ss[jj] += __shfl_xor(ss[jj], 4);
    ss[jj] += __shfl_xor(ss[jj], 8);
    ss[jj] = rsqrtf(ss[jj] * (1.0f / 256.0f) + 1e-5f) * OML;
  }
  #pragma unroll
  for (int nf = 0; nf < 16; ++nf) {
    const int dcol = nf * 16 + l15;
    const float sw = subln[dcol];
    #pragma unroll
    for (int jj = 0; jj < 4; ++jj) {
      const int t = q0w + lg * 4 + jj;
      attn_out[(size_t)t * HIDN + pair * VD + dcol] = f2bf(oacc0[nf][jj] * ss[jj] * sw);
    }
  }
}

extern "C" void kernel_launch(void* const* d_in, const int* in_sizes, int n_in,
                              void* d_out, int out_size, void* d_ws, size_t ws_size,
                              hipStream_t stream) {
  (void)in_sizes; (void)n_in; (void)out_size; (void)ws_size;
  const float* hs     = (const float*)d_in[0];
  const float* wqkv_w = (const float*)d_in[1];
  const float* wqkv_b = (const float*)d_in[2];
  const float* lq1    = (const float*)d_in[3];
  const float* lk1    = (const float*)d_in[4];
  const float* lq2    = (const float*)d_in[5];
  const float* lk2    = (const float*)d_in[6];
  const float* subln  = (const float*)d_in[7];
  const float* out_w  = (const float*)d_in[8];
  const float* out_b  = (const float*)d_in[9];

  // ws layout (all bf16/ushort):
  //   qq [2048][4096] | ctt 4x1048576 | attn_out [2048][4096]
  //   hs_bf [2048*4096] | wqkv_bf [6144*4096] | outw_bf [4096*4096]   (~126 MB)
  unsigned short* qq       = (unsigned short*)d_ws;
  unsigned short* ctt      = qq + (size_t)TTOK * HIDN;
  unsigned short* attn_out = ctt + (size_t)4 * 1048576;
  unsigned short* hs_bf    = attn_out + (size_t)TTOK * HIDN;
  unsigned short* wqkv_bf  = hs_bf + (size_t)TTOK * HIDN;
  unsigned short* outw_bf  = wqkv_bf + (size_t)OPD * HIDN;

  const int nb0 = (TTOK * HIDN) >> 11;          // 4096
  const int nb1 = (OPD * HIDN) >> 11;           // 12288
  const int nb2 = (HIDN * HIDN) >> 11;          // 8192
  cvt3<<<dim3(nb0 + nb1 + nb2), 256, 0, stream>>>(
      hs, hs_bf, nb0, wqkv_w, wqkv_bf, nb1, out_w, outw_bf);

  // GEMM1: Q -> qq row-major; K/V -> ctt tiled
  gemm_bf16<true, true><<<dim3(OPD / 128, TTOK / 128), 256, 0, stream>>>(
      hs_bf, wqkv_bf, wqkv_b, qq, ctt, HIDN, HIDN, HIDN, HIDN);

  // Attention + combine + RMSNorm -> attn_out (bf16)
  attn_kernel<<<dim3(512), 256, 0, stream>>>(
      qq, ctt, lq1, lk1, lq2, lk2, subln, attn_out);

  // GEMM2: out = attn_out @ out_w^T + out_b  (fp32 out)
  gemm_bf16<false, false><<<dim3(HIDN / 128, TTOK / 128), 256, 0, stream>>>(
      attn_out, outw_bf, out_b, d_out, nullptr, HIDN, HIDN, HIDN, HIDN);
}

// Round 5
// 412.824 us; speedup vs baseline: 2.0669x; 1.0669x over previous
//
#include <hip/hip_runtime.h>

#define TTOK 2048
#define HIDN 4096
#define OPD  6144
#define DH   128
#define VD   256
#define KOFF 4096
#define VOFF 5120

typedef short  s16x8 __attribute__((ext_vector_type(8)));
typedef unsigned short u16x8 __attribute__((ext_vector_type(8)));
typedef float  fx4   __attribute__((ext_vector_type(4)));

constexpr float LAM_INIT = 0.7455692280263534f;
constexpr float OML      = 1.0f - LAM_INIT;          // (1 - lambda_init)
constexpr float QKSCALE  = 0.08838834764831845f;     // 128^-0.5
constexpr float RESCALE_THR = 8.0f;

__device__ __forceinline__ unsigned short f2bf(float f) {
  unsigned int u = __builtin_bit_cast(unsigned int, f);
  u += 0x7fffu + ((u >> 16) & 1u);   // RNE
  return (unsigned short)(u >> 16);
}

__device__ __forceinline__ void g2l16(const void* gsrc, void* ldst) {
  __builtin_amdgcn_global_load_lds(
      (const __attribute__((address_space(1))) unsigned int*)gsrc,
      (__attribute__((address_space(3))) unsigned int*)ldst, 16, 0, 0);
}

// fp32 -> bf16 bulk convert, 3 tensors, 2048 elems/block (all sizes % 2048 == 0)
__global__ __launch_bounds__(256)
void cvt3(const float* __restrict__ s0, unsigned short* __restrict__ d0, int nb0,
          const float* __restrict__ s1, unsigned short* __restrict__ d1, int nb1,
          const float* __restrict__ s2, unsigned short* __restrict__ d2)
{
  const int b = blockIdx.x;
  const float* s; unsigned short* d; int base;
  if (b < nb0)            { s = s0; d = d0; base = b << 11; }
  else if (b < nb0 + nb1) { s = s1; d = d1; base = (b - nb0) << 11; }
  else                    { s = s2; d = d2; base = (b - nb0 - nb1) << 11; }
  const int i = base + (int)threadIdx.x * 8;
  const float4 a0 = *(const float4*)(s + i);
  const float4 a1 = *(const float4*)(s + i + 4);
  u16x8 v;
  v[0]=f2bf(a0.x); v[1]=f2bf(a0.y); v[2]=f2bf(a0.z); v[3]=f2bf(a0.w);
  v[4]=f2bf(a1.x); v[5]=f2bf(a1.y); v[6]=f2bf(a1.z); v[7]=f2bf(a1.w);
  *(u16x8*)(d + i) = v;
}

// C[M,N] = A[M,K] * B[N,K]^T + bias.  A,B bf16 row-major. m97 structure:
// DOUBLE-BUFFERED global_load_lds(16B) staging into linear [128][32] LDS,
// one barrier per K-step, prefetch of tile t+1 overlaps tile t's MFMAs.
// QKVOUT: Q region -> Cp row-major bf16; K/V regions -> ctt tiled layout:
//   per (kvp, ktile): 16384 elems = [K: cc(32)x key(32)x c8(8)] [V: kc(4)x d(256)x k8(8)]
template<bool QKVOUT, bool OUTBF16>
__global__ __launch_bounds__(256)
void gemm_bf16(const unsigned short* __restrict__ A, const unsigned short* __restrict__ B,
               const float* __restrict__ bias, void* __restrict__ Cp,
               unsigned short* __restrict__ ctt, int K, int lda, int ldb, int ldc)
{
  __shared__ __align__(16) unsigned short As[2][128 * 32];
  __shared__ __align__(16) unsigned short Bs[2][128 * 32];
  const int tid  = threadIdx.x;
  const int lane = tid & 63, wid = tid >> 6;
  const int wr = wid >> 1, wc = wid & 1;       // 2x2 wave grid, 64x64 out each
  const int m0 = blockIdx.y * 128, n0 = blockIdx.x * 128;
  const int l15 = lane & 15, lg = lane >> 4;
  const int row = tid >> 2;                    // 0..63
  const int c8  = (tid & 3) << 3;

  fx4 acc[4][4] = {};

  // stage K-tile (32 cols) starting at col kt into buffer buf
  auto stage = [&](int kt, int buf) {
    #pragma unroll
    for (int it = 0; it < 2; ++it) {
      const int r  = it * 64 + row;
      const int s2 = it * 256 + tid;
      g2l16(A + (size_t)(m0 + r) * lda + kt + c8, &As[buf][s2 * 8]);
      g2l16(B + (size_t)(n0 + r) * ldb + kt + c8, &Bs[buf][s2 * 8]);
    }
  };

  stage(0, 0);
  const int nk = K >> 5;
  for (int t = 0; t < nk; ++t) {
    __syncthreads();                     // tile t landed (vmcnt drain); buf^1 free
    if (t + 1 < nk) stage((t + 1) << 5, (t + 1) & 1);
    const unsigned short* as = As[t & 1];
    const unsigned short* bs = Bs[t & 1];
    s16x8 af[4], bf[4];
    #pragma unroll
    for (int i = 0; i < 4; ++i) {
      af[i] = *(const s16x8*)&as[(wr * 64 + i * 16 + l15) * 32 + lg * 8];
      bf[i] = *(const s16x8*)&bs[(wc * 64 + i * 16 + l15) * 32 + lg * 8];
    }
    #pragma unroll
    for (int mi = 0; mi < 4; ++mi)
      #pragma unroll
      for (int ni = 0; ni < 4; ++ni)
        acc[mi][ni] = __builtin_amdgcn_mfma_f32_16x16x32_bf16(af[mi], bf[ni], acc[mi][ni], 0, 0, 0);
  }

  const int r0 = m0 + wr * 64;
  const int c0 = n0 + wc * 64;
  if (QKVOUT && n0 >= VOFF) {
    // V region -> ctt tiled, ushort4 over 4 consecutive keys
    #pragma unroll
    for (int mi = 0; mi < 4; ++mi)
      #pragma unroll
      for (int ni = 0; ni < 4; ++ni) {
        const int col = c0 + ni * 16 + l15;
        const float bv = bias[col];
        const fx4 a = acc[mi][ni];
        ushort4 pk;
        pk.x = f2bf(a[0] + bv); pk.y = f2bf(a[1] + bv);
        pk.z = f2bf(a[2] + bv); pk.w = f2bf(a[3] + bv);
        const int d   = col - VOFF;
        const int kvp = d >> 8, dw = d & 255;
        const int row0 = r0 + mi * 16 + lg * 4;      // key
        const int kt2 = row0 >> 5, kk = row0 & 31;
        const int kc = kk >> 3, k8 = kk & 7;
        *(ushort4*)&ctt[(size_t)kvp * 1048576 + (size_t)kt2 * 16384 + 8192
                        + kc * 2048 + dw * 8 + k8] = pk;
      }
  } else if (QKVOUT && n0 >= KOFF) {
    // K region -> ctt tiled, scalar stores
    #pragma unroll
    for (int mi = 0; mi < 4; ++mi)
      #pragma unroll
      for (int ni = 0; ni < 4; ++ni) {
        const int ccol = c0 + ni * 16 + l15 - KOFF;  // 0..1023
        const float bv = bias[c0 + ni * 16 + l15];
        const int kvp = ccol >> 8, cw = ccol & 255;
        const int cc = cw >> 3, cb = cw & 7;
        const fx4 a = acc[mi][ni];
        #pragma unroll
        for (int jj = 0; jj < 4; ++jj) {
          const int row2 = r0 + mi * 16 + lg * 4 + jj;   // key
          const int kt2 = row2 >> 5, kk = row2 & 31;
          ctt[(size_t)kvp * 1048576 + (size_t)kt2 * 16384 + cc * 256 + kk * 8 + cb]
              = f2bf(a[jj] + bv);
        }
      }
  } else {
    #pragma unroll
    for (int mi = 0; mi < 4; ++mi)
      #pragma unroll
      for (int ni = 0; ni < 4; ++ni) {
        const int col = c0 + ni * 16 + l15;
        const float bv = bias[col];
        const fx4 a = acc[mi][ni];
        #pragma unroll
        for (int jj = 0; jj < 4; ++jj) {
          const int row2 = r0 + mi * 16 + lg * 4 + jj;
          const float v = a[jj] + bv;
          if (OUTBF16) ((unsigned short*)Cp)[(size_t)row2 * ldc + col] = f2bf(v);
          else         ((float*)Cp)[(size_t)row2 * ldc + col] = v;
        }
      }
  }
}

// Block = (pair, 64 q-rows), 4 waves (16 rows each, both diff components).
// K/V staged per 32-key tile via global_load_lds from the tile-contiguous ctt,
// double-buffered, ONE barrier per tile. All fragment ds_reads conflict-free.
__global__ __launch_bounds__(256, 2)
void attn_kernel(const unsigned short* __restrict__ qq,    // [TTOK][HIDN] bf16 Q
                 const unsigned short* __restrict__ ctt,   // tiled K/V
                 const float* __restrict__ lq1, const float* __restrict__ lk1,
                 const float* __restrict__ lq2, const float* __restrict__ lk2,
                 const float* __restrict__ subln,
                 unsigned short* __restrict__ attn_out)    // [TTOK][HIDN] bf16
{
  __shared__ __align__(16) unsigned short Sb[2][16384];    // [K 16KB][V 16KB]
  __shared__ __align__(16) unsigned short Pl[4][2][640];
  const int tid = threadIdx.x;
  const int lane = tid & 63, w = tid >> 6;
  const int l15 = lane & 15, lg = lane >> 4;

  // block decode: kvp -> XCD affinity, heavy q-blocks first
  const int bid = blockIdx.x;
  const int g = bid & 7, s = bid >> 3;
  const int kvp  = g >> 1;
  const int pair = kvp * 4 + (s & 3);
  const int qb   = 31 - ((s >> 2) << 1) - (g & 1);
  const int q0b  = qb * 64;
  const int q0w  = q0b + w * 16;
  const int nt   = 2 * qb + 2;

  const unsigned short* cbase = ctt + (size_t)kvp * 1048576;

  // stage tile kt (32KB linear) into Sb[buf]: 8 x global_load_lds(16B) per wave
  auto stage = [&](int kt, int buf) {
    const unsigned short* src = cbase + (size_t)kt * 16384;
    const int off = w * 512 + lane * 8;
    #pragma unroll
    for (int i = 0; i < 8; ++i) {
      const int o = i * 2048 + off;
      g2l16(src + o, &Sb[buf][o]);
    }
  };

  stage(0, 0);

  // lambda via wave-parallel dot
  float a1 = lq1[lane] * lk1[lane] + lq1[lane + 64] * lk1[lane + 64];
  float a2 = lq2[lane] * lk2[lane] + lq2[lane + 64] * lk2[lane + 64];
  #pragma unroll
  for (int sft = 1; sft < 64; sft <<= 1) { a1 += __shfl_xor(a1, sft); a2 += __shfl_xor(a2, sft); }
  const float lam = __expf(a1) - __expf(a2) + LAM_INIT;

  // Q fragments
  s16x8 qf0[4], qf1[4];
  {
    const unsigned short* qbp = qq + (size_t)(q0w + l15) * HIDN + pair * VD + lg * 8;
    #pragma unroll
    for (int kf = 0; kf < 4; ++kf) {
      qf0[kf] = *(const s16x8*)(qbp + kf * 32);
      qf1[kf] = *(const s16x8*)(qbp + DH + kf * 32);
    }
  }

  float mrun0 = -1e30f, mrun1 = -1e30f;
  float lrun0 = 0.f, lrun1 = 0.f;
  fx4 oacc0[16] = {}, oacc1[16] = {};
  unsigned short* pl0 = &Pl[w][0][0];
  unsigned short* pl1 = &Pl[w][1][0];
  const int q = q0w + l15;
  const int qmax = q0w + 15;

  for (int t = 0; t < nt; ++t) {
    __syncthreads();                      // stage(t) visible; buf[(t+1)&1] free
    if (t + 1 < nt) stage(t + 1, (t + 1) & 1);
    const int kb = t * 32;
    if (kb > qmax) continue;              // wave-uniform; still hits barrier next iter
    const unsigned short* Kl = Sb[t & 1];
    const unsigned short* Vl = Sb[t & 1] + 8192;

    // ---- QK^T swapped: S^T[key][q]
    fx4 s00 = {0,0,0,0}, s01 = {0,0,0,0}, s10 = {0,0,0,0}, s11 = {0,0,0,0};
    #pragma unroll
    for (int kf = 0; kf < 4; ++kf) {
      const int cc0 = kf * 4 + lg;        // comp0 chunks
      const int cc1 = 16 + kf * 4 + lg;   // comp1 chunks
      const s16x8 k00 = *(const s16x8*)&Kl[cc0 * 256 + l15 * 8];
      const s16x8 k01 = *(const s16x8*)&Kl[cc0 * 256 + (16 + l15) * 8];
      const s16x8 k10 = *(const s16x8*)&Kl[cc1 * 256 + l15 * 8];
      const s16x8 k11 = *(const s16x8*)&Kl[cc1 * 256 + (16 + l15) * 8];
      s00 = __builtin_amdgcn_mfma_f32_16x16x32_bf16(k00, qf0[kf], s00, 0, 0, 0);
      s01 = __builtin_amdgcn_mfma_f32_16x16x32_bf16(k01, qf0[kf], s01, 0, 0, 0);
      s10 = __builtin_amdgcn_mfma_f32_16x16x32_bf16(k10, qf1[kf], s10, 0, 0, 0);
      s11 = __builtin_amdgcn_mfma_f32_16x16x32_bf16(k11, qf1[kf], s11, 0, 0, 0);
    }

    // ---- mask + scale
    float v0[8], v1[8];
    #pragma unroll
    for (int j = 0; j < 4; ++j) {
      const int klo = kb + lg * 4 + j, khi = klo + 16;
      v0[j]     = (klo <= q) ? s00[j] * QKSCALE : -1e30f;
      v0[4 + j] = (khi <= q) ? s01[j] * QKSCALE : -1e30f;
      v1[j]     = (klo <= q) ? s10[j] * QKSCALE : -1e30f;
      v1[4 + j] = (khi <= q) ? s11[j] * QKSCALE : -1e30f;
    }
    // ---- tile max per comp
    float tm0 = fmaxf(fmaxf(fmaxf(v0[0],v0[1]),fmaxf(v0[2],v0[3])),
                      fmaxf(fmaxf(v0[4],v0[5]),fmaxf(v0[6],v0[7])));
    float tm1 = fmaxf(fmaxf(fmaxf(v1[0],v1[1]),fmaxf(v1[2],v1[3])),
                      fmaxf(fmaxf(v1[4],v1[5]),fmaxf(v1[6],v1[7])));
    tm0 = fmaxf(tm0, __shfl_xor(tm0, 16)); tm0 = fmaxf(tm0, __shfl_xor(tm0, 32));
    tm1 = fmaxf(tm1, __shfl_xor(tm1, 16)); tm1 = fmaxf(tm1, __shfl_xor(tm1, 32));

    // ---- defer-max rescale (rare)
    const bool need = (tm0 > mrun0 + RESCALE_THR) || (tm1 > mrun1 + RESCALE_THR);
    if (__any(need)) {
      const float mn0 = fmaxf(mrun0, tm0), mn1 = fmaxf(mrun1, tm1);
      const float fac0 = __expf(mrun0 - mn0), fac1 = __expf(mrun1 - mn1);
      mrun0 = mn0; mrun1 = mn1;
      lrun0 *= fac0; lrun1 *= fac1;
      #pragma unroll
      for (int jj = 0; jj < 4; ++jj) {
        const float fr0 = __shfl(fac0, lg * 4 + jj);
        const float fr1 = __shfl(fac1, lg * 4 + jj);
        #pragma unroll
        for (int nf = 0; nf < 16; ++nf) { oacc0[nf][jj] *= fr0; oacc1[nf][jj] *= fr1; }
      }
    }

    // ---- P = exp(v - mrun), pack bf16 -> per-wave LDS transpose
    {
      float ps0 = 0.f, ps1 = 0.f;
      ushort4 lo0, hi0, lo1, hi1;
      float p;
      p = __expf(v0[0]-mrun0); ps0 += p; lo0.x = f2bf(p);
      p = __expf(v0[1]-mrun0); ps0 += p; lo0.y = f2bf(p);
      p = __expf(v0[2]-mrun0); ps0 += p; lo0.z = f2bf(p);
      p = __expf(v0[3]-mrun0); ps0 += p; lo0.w = f2bf(p);
      p = __expf(v0[4]-mrun0); ps0 += p; hi0.x = f2bf(p);
      p = __expf(v0[5]-mrun0); ps0 += p; hi0.y = f2bf(p);
      p = __expf(v0[6]-mrun0); ps0 += p; hi0.z = f2bf(p);
      p = __expf(v0[7]-mrun0); ps0 += p; hi0.w = f2bf(p);
      p = __expf(v1[0]-mrun1); ps1 += p; lo1.x = f2bf(p);
      p = __expf(v1[1]-mrun1); ps1 += p; lo1.y = f2bf(p);
      p = __expf(v1[2]-mrun1); ps1 += p; lo1.z = f2bf(p);
      p = __expf(v1[3]-mrun1); ps1 += p; lo1.w = f2bf(p);
      p = __expf(v1[4]-mrun1); ps1 += p; hi1.x = f2bf(p);
      p = __expf(v1[5]-mrun1); ps1 += p; hi1.y = f2bf(p);
      p = __expf(v1[6]-mrun1); ps1 += p; hi1.z = f2bf(p);
      p = __expf(v1[7]-mrun1); ps1 += p; hi1.w = f2bf(p);
      lrun0 += ps0; lrun1 += ps1;
      *(ushort4*)&pl0[l15 * 40 + lg * 4]      = lo0;
      *(ushort4*)&pl0[l15 * 40 + 16 + lg * 4] = hi0;
      *(ushort4*)&pl1[l15 * 40 + lg * 4]      = lo1;
      *(ushort4*)&pl1[l15 * 40 + 16 + lg * 4] = hi1;
    }
    asm volatile("s_waitcnt lgkmcnt(0)" ::: "memory");
    __builtin_amdgcn_sched_barrier(0);

    // ---- PV from LDS V tile (conflict-free layout)
    const s16x8 pa0 = *(const s16x8*)&pl0[l15 * 40 + lg * 8];
    const s16x8 pa1 = *(const s16x8*)&pl1[l15 * 40 + lg * 8];
    #pragma unroll
    for (int nf = 0; nf < 16; ++nf) {
      const s16x8 vf = *(const s16x8*)&Vl[lg * 2048 + (nf * 16 + l15) * 8];
      oacc0[nf] = __builtin_amdgcn_mfma_f32_16x16x32_bf16(pa0, vf, oacc0[nf], 0, 0, 0);
      oacc1[nf] = __builtin_amdgcn_mfma_f32_16x16x32_bf16(pa1, vf, oacc1[nf], 0, 0, 0);
    }
  }

  // ---- finalize row sums
  lrun0 += __shfl_xor(lrun0, 16); lrun0 += __shfl_xor(lrun0, 32);
  lrun1 += __shfl_xor(lrun1, 16); lrun1 += __shfl_xor(lrun1, 32);

  float li0[4], li1[4];
  #pragma unroll
  for (int jj = 0; jj < 4; ++jj) {
    li0[jj] = 1.0f / __shfl(lrun0, lg * 4 + jj);
    li1[jj] = 1.0f / __shfl(lrun1, lg * 4 + jj);
  }

  // ---- combine, RMSNorm over 256, scale, store
  float ss[4] = {0.f, 0.f, 0.f, 0.f};
  #pragma unroll
  for (int nf = 0; nf < 16; ++nf)
    #pragma unroll
    for (int jj = 0; jj < 4; ++jj) {
      const float o = oacc0[nf][jj] * li0[jj] - lam * oacc1[nf][jj] * li1[jj];
      oacc0[nf][jj] = o;
      ss[jj] += o * o;
    }
  #pragma unroll
  for (int jj = 0; jj < 4; ++jj) {
    ss[jj] += __shfl_xor(ss[jj], 1);
    ss[jj] += __shfl_xor(ss[jj], 2);
    ss[jj] += __shfl_xor(ss[jj], 4);
    ss[jj] += __shfl_xor(ss[jj], 8);
    ss[jj] = rsqrtf(ss[jj] * (1.0f / 256.0f) + 1e-5f) * OML;
  }
  #pragma unroll
  for (int nf = 0; nf < 16; ++nf) {
    const int dcol = nf * 16 + l15;
    const float sw = subln[dcol];
    #pragma unroll
    for (int jj = 0; jj < 4; ++jj) {
      const int t = q0w + lg * 4 + jj;
      attn_out[(size_t)t * HIDN + pair * VD + dcol] = f2bf(oacc0[nf][jj] * ss[jj] * sw);
    }
  }
}

extern "C" void kernel_launch(void* const* d_in, const int* in_sizes, int n_in,
                              void* d_out, int out_size, void* d_ws, size_t ws_size,
                              hipStream_t stream) {
  (void)in_sizes; (void)n_in; (void)out_size; (void)ws_size;
  const float* hs     = (const float*)d_in[0];
  const float* wqkv_w = (const float*)d_in[1];
  const float* wqkv_b = (const float*)d_in[2];
  const float* lq1    = (const float*)d_in[3];
  const float* lk1    = (const float*)d_in[4];
  const float* lq2    = (const float*)d_in[5];
  const float* lk2    = (const float*)d_in[6];
  const float* subln  = (const float*)d_in[7];
  const float* out_w  = (const float*)d_in[8];
  const float* out_b  = (const float*)d_in[9];

  // ws layout (all bf16/ushort):
  //   qq [2048][4096] | ctt 4x1048576 | attn_out [2048][4096]
  //   hs_bf [2048*4096] | wqkv_bf [6144*4096] | outw_bf [4096*4096]   (~126 MB)
  unsigned short* qq       = (unsigned short*)d_ws;
  unsigned short* ctt      = qq + (size_t)TTOK * HIDN;
  unsigned short* attn_out = ctt + (size_t)4 * 1048576;
  unsigned short* hs_bf    = attn_out + (size_t)TTOK * HIDN;
  unsigned short* wqkv_bf  = hs_bf + (size_t)TTOK * HIDN;
  unsigned short* outw_bf  = wqkv_bf + (size_t)OPD * HIDN;

  const int nb0 = (TTOK * HIDN) >> 11;          // 4096
  const int nb1 = (OPD * HIDN) >> 11;           // 12288
  const int nb2 = (HIDN * HIDN) >> 11;          // 8192
  cvt3<<<dim3(nb0 + nb1 + nb2), 256, 0, stream>>>(
      hs, hs_bf, nb0, wqkv_w, wqkv_bf, nb1, out_w, outw_bf);

  // GEMM1: Q -> qq row-major; K/V -> ctt tiled
  gemm_bf16<true, true><<<dim3(OPD / 128, TTOK / 128), 256, 0, stream>>>(
      hs_bf, wqkv_bf, wqkv_b, qq, ctt, HIDN, HIDN, HIDN, HIDN);

  // Attention + combine + RMSNorm -> attn_out (bf16)
  attn_kernel<<<dim3(512), 256, 0, stream>>>(
      qq, ctt, lq1, lk1, lq2, lk2, subln, attn_out);

  // GEMM2: out = attn_out @ out_w^T + out_b  (fp32 out)
  gemm_bf16<false, false><<<dim3(HIDN / 128, TTOK / 128), 256, 0, stream>>>(
      attn_out, outw_bf, out_b, d_out, nullptr, HIDN, HIDN, HIDN, HIDN);
}